// Round 5
// baseline (179.852 us; speedup 1.0000x reference)
//
#include <hip/hip_runtime.h>
#include <math.h>

#define NPTS 4096
#define MPTS 4096
#define NSTEPS 8
#define ICP_TOL 1e-6f
#define NBLK 512    // 2 blocks/CU @ launch_bounds(256,2): proven resident (R5-R12)
#define NSUB 32     // arrival sub-counters, 16 blocks each

// ws layout (floats):
//   ptgt4 : [0, 32768)         interleaved {x,y,z,0.5*|t|^2}, 2*4096 targets
//   acc   : [32768, 98304)     [step][block(512)][16] per-block partials (atomic stores)
//   ctrs  : words at 98304, 1536/step: subs at c*16 (c<32), master at 512,
//           flags at 1024+f*16 (f<32); value 0=wait, 1=released
#define ACC_OFF 32768
#define CTR_OFF 98304
#define CTR_STRIDE 1536

__global__ void init_kernel(const float* __restrict__ ptgt, float* __restrict__ ws) {
    float* ptgt4 = ws;
    unsigned* ctrs = (unsigned*)(ws + CTR_OFF);
    int gid = blockIdx.x * 256 + threadIdx.x;   // 8192 threads
    if (gid < 2 * MPTS) {
        float x = ptgt[3 * gid + 0];
        float y = ptgt[3 * gid + 1];
        float z = ptgt[3 * gid + 2];
        float4 v;
        v.x = x; v.y = y; v.z = z;
        v.w = 0.5f * (x * x + y * y + z * z);
        ((float4*)ptgt4)[gid] = v;
    }
    for (int i = gid; i < NSTEPS * CTR_STRIDE; i += 8192) ctrs[i] = 0u;
}

__device__ __forceinline__ float frcp(float x) {
#if __has_builtin(__builtin_amdgcn_rcpf)
    return __builtin_amdgcn_rcpf(x);
#else
    return 1.f / x;
#endif
}
__device__ __forceinline__ float frsq(float x) {
#if __has_builtin(__builtin_amdgcn_rsqf)
    return __builtin_amdgcn_rsqf(x);
#else
    return 1.f / sqrtf(x);
#endif
}

#define DET3(a,b,c,d,e,f,g,h,i) \
    ((a)*((e)*(i)-(f)*(h)) - (b)*((d)*(i)-(f)*(g)) + (c)*((d)*(h)-(e)*(g)))

// Max-eigenpair of symmetric 4x4 via Newton on the characteristic quartic
// (monotone from Gershgorin upper bound) + cofactor-row eigenvector.
// R13: 8 Newton iterations (quadratic convergence; rel err < 1e-12 by 8).
__device__ __forceinline__ void horn_quat(const float N[4][4], float q[4]) {
    float s = 1e-30f;
#pragma unroll
    for (int i = 0; i < 4; ++i)
#pragma unroll
        for (int j = 0; j < 4; ++j) s = fmaxf(s, fabsf(N[i][j]));
    float inv = frcp(s);
    float A[4][4], B[4][4];
#pragma unroll
    for (int i = 0; i < 4; ++i)
#pragma unroll
        for (int j = 0; j < 4; ++j) A[i][j] = N[i][j] * inv;
#pragma unroll
    for (int i = 0; i < 4; ++i)
#pragma unroll
        for (int j = i; j < 4; ++j) {
            float v = A[i][0]*A[0][j] + A[i][1]*A[1][j] + A[i][2]*A[2][j] + A[i][3]*A[3][j];
            B[i][j] = v; B[j][i] = v;
        }
    float p1 = A[0][0]+A[1][1]+A[2][2]+A[3][3];
    float p2 = B[0][0]+B[1][1]+B[2][2]+B[3][3];
    float p3 = 0.f, p4 = 0.f;
#pragma unroll
    for (int i = 0; i < 4; ++i)
#pragma unroll
        for (int j = 0; j < 4; ++j) { p3 += A[i][j]*B[i][j]; p4 += B[i][j]*B[i][j]; }
    float e1 = p1;
    float e2 = 0.5f*(e1*p1 - p2);
    float e3 = (e2*p1 - e1*p2 + p3)*(1.f/3.f);
    float e4 = 0.25f*(e3*p1 - e2*p2 + e1*p3 - p4);
    float lam = -3e38f;
#pragma unroll
    for (int i = 0; i < 4; ++i) {
        float r = A[i][i];
#pragma unroll
        for (int j = 0; j < 4; ++j) if (j != i) r += fabsf(A[i][j]);
        lam = fmaxf(lam, r);
    }
#pragma unroll
    for (int it = 0; it < 8; ++it) {
        float pv = (((lam - e1)*lam + e2)*lam - e3)*lam + e4;
        float dv = ((4.f*lam - 3.f*e1)*lam + 2.f*e2)*lam - e3;
        lam -= pv * frcp(dv);
    }
    float M[4][4];
#pragma unroll
    for (int i = 0; i < 4; ++i)
#pragma unroll
        for (int j = 0; j < 4; ++j) M[i][j] = A[i][j] - ((i == j) ? lam : 0.f);
    float C0 = DET3(M[1][1],M[1][2],M[1][3], M[2][1],M[2][2],M[2][3], M[3][1],M[3][2],M[3][3]);
    float C1 = DET3(M[0][0],M[0][2],M[0][3], M[2][0],M[2][2],M[2][3], M[3][0],M[3][2],M[3][3]);
    float C2 = DET3(M[0][0],M[0][1],M[0][3], M[1][0],M[1][1],M[1][3], M[3][0],M[3][1],M[3][3]);
    float C3 = DET3(M[0][0],M[0][1],M[0][2], M[1][0],M[1][1],M[1][2], M[2][0],M[2][1],M[2][2]);
    int is = 0; float cb = fabsf(C0);
    if (fabsf(C1) > cb) { cb = fabsf(C1); is = 1; }
    if (fabsf(C2) > cb) { cb = fabsf(C2); is = 2; }
    if (fabsf(C3) > cb) { cb = fabsf(C3); is = 3; }
    float v0, v1, v2, v3;
#define ROWCOF(a,b,c) { \
    v0 =  DET3(M[a][1],M[a][2],M[a][3], M[b][1],M[b][2],M[b][3], M[c][1],M[c][2],M[c][3]); \
    v1 = -DET3(M[a][0],M[a][2],M[a][3], M[b][0],M[b][2],M[b][3], M[c][0],M[c][2],M[c][3]); \
    v2 =  DET3(M[a][0],M[a][1],M[a][3], M[b][0],M[b][1],M[b][3], M[c][0],M[c][1],M[c][3]); \
    v3 = -DET3(M[a][0],M[a][1],M[a][2], M[b][0],M[b][1],M[b][2], M[c][0],M[c][1],M[c][2]); }
    if (is == 0)      ROWCOF(1,2,3)
    else if (is == 1) ROWCOF(0,2,3)
    else if (is == 2) ROWCOF(0,1,3)
    else              ROWCOF(0,1,2)
#undef ROWCOF
    float nr = frsq(v0*v0 + v1*v1 + v2*v2 + v3*v3);
    q[0] = v0*nr; q[1] = v1*nr; q[2] = v2*nr; q[3] = v3*nr;
}

#define FOR16(OP) OP(0) OP(1) OP(2) OP(3) OP(4) OP(5) OP(6) OP(7) \
                  OP(8) OP(9) OP(10) OP(11) OP(12) OP(13) OP(14) OP(15)

// 512 blocks x 256 threads, persistent (2 blocks/CU). R13 structure:
// NN (16 pts hoisted to regs, depth-3 prefetch) -> butterfly argmax ->
// parallel block-combine (64-thread quarters + tree) -> acc store -> R9
// counter barrier -> PER-BATCH gather (16 loads/thread own batch; tid>=192
// sum other batch's err column in parallel) -> 2-level tree reduce -> tid0
// conv+solve (Horn, 8 Newton its) -> next step. Final step: workers return
// after arrival; blocks 0 AND 256 each solve + write their batch's out row.
// fp reassociation vs R12 accepted (absmax drift ~1e-5, solver offset is
// 1.6e-3). Fence-free visibility pattern proven R5-R12.
__global__ __launch_bounds__(256, 2) void icp_main(
    const float* __restrict__ psrc, float* __restrict__ ws,
    float* __restrict__ out) {

    float* ptgt4 = ws;
    float* acc = ws + ACC_OFF;
    unsigned* ctrs = (unsigned*)(ws + CTR_OFF);

    __shared__ float st[2][13];     // own batch row used: Rcum(9), tcum(3), err(1)
    __shared__ unsigned keys[4][16];
    __shared__ float red[16][16];
    __shared__ float rq[4][16];     // block-combine quarter partials
    __shared__ float gred[16][16];  // gather partials [group][comp]
    __shared__ float gq[4][16];     // gather quarter partials
    __shared__ float oerr[64];      // other-batch err partials
    __shared__ float oe2[8];
    __shared__ float asumv[16];     // own-batch totals
    __shared__ float oerrF;         // other-batch err total
    __shared__ float oErrPrev;      // other-batch previous err
    __shared__ int contflag;        // 1=continue, 2=done

    const int tid = threadIdx.x;
    const int bid = blockIdx.x;
    const int b = bid >> 8;             // batch (256 blocks each)
    const int n0 = (bid & 255) * 16;    // this block's 16 source points

    if (tid == 0) {
        st[b][0] = 1.f; st[b][1] = 0.f; st[b][2] = 0.f;
        st[b][3] = 0.f; st[b][4] = 1.f; st[b][5] = 0.f;
        st[b][6] = 0.f; st[b][7] = 0.f; st[b][8] = 1.f;
        st[b][9] = 0.f; st[b][10] = 0.f; st[b][11] = 0.f;
        st[b][12] = 0.f;
        oErrPrev = 0.f;
    }
    __syncthreads();

    const int w = tid >> 6, lane = tid & 63;
    const int m0 = w * 1024 + lane;
    const float4* tpb = (const float4*)ptgt4 + ((size_t)b * MPTS + m0);
    const float* ps = psrc + ((size_t)b * NPTS + n0) * 3;

    // hoist the 16 source points into registers (constant indices -> VGPRs)
    float sx[16], sy[16], sz[16];
#define HOIST(i) { sx[i] = ps[3*(i)]; sy[i] = ps[3*(i)+1]; sz[i] = ps[3*(i)+2]; }
    FOR16(HOIST)
#undef HOIST

    for (int step = 0; step < NSTEPS; ++step) {
        float R00 = st[b][0], R01 = st[b][1], R02 = st[b][2];
        float R10 = st[b][3], R11 = st[b][4], R12 = st[b][5];
        float R20 = st[b][6], R21 = st[b][7], R22 = st[b][8];
        float t0 = st[b][9], t1 = st[b][10], t2 = st[b][11];

#define DECLP(i) float px##i, py##i, pz##i;
        FOR16(DECLP)
#undef DECLP
#define LOADP(i) { float x = sx[i], y = sy[i], z = sz[i]; \
        px##i = fmaf(R00, x, fmaf(R01, y, fmaf(R02, z, t0))); \
        py##i = fmaf(R10, x, fmaf(R11, y, fmaf(R12, z, t1))); \
        pz##i = fmaf(R20, x, fmaf(R21, y, fmaf(R22, z, t2))); }
        FOR16(LOADP)
#undef LOADP

        // s = p.t - |t|^2/2; argmax s == argmin dist (strict > keeps first max)
#define DECLB(i) float bs##i = -3.0e38f; int ix##i = m0;
        FOR16(DECLB)
#undef DECLB

        float4 tc0 = tpb[0];
        float4 tc1 = tpb[64];
        float4 tc2 = tpb[128];
        int mreg = m0;
#pragma unroll
        for (int k = 0; k < 16; ++k) {
            float4 tnx = tpb[((k + 3) & 15) * 64];  // wraps harmlessly
            float tx = tc0.x, ty = tc0.y, tz = tc0.z, htn = tc0.w;
#define PAIR(i) { float s = fmaf(px##i, tx, fmaf(py##i, ty, fmaf(pz##i, tz, -htn))); \
            if (s > bs##i) { bs##i = s; ix##i = mreg; } }
            FOR16(PAIR)
#undef PAIR
            mreg += 64;
            tc0 = tc1;
            tc1 = tc2;
            tc2 = tnx;
        }

        // ---- wave argmax: order-preserving packed key (score hi-20 |
        // 4095-m), payload-halving fold butterfly (32 shuffles, HW-verified
        // bitwise == 96-shuffle tree, R11/R12). ----
        unsigned k_[16];
#define MKKEY(i) { unsigned ub = __float_as_uint(bs##i); \
        unsigned u = ((int)ub >= 0) ? (ub | 0x80000000u) : ~ub; \
        k_[i] = (u & 0xFFFFF000u) | (4095u - (unsigned)ix##i); }
        FOR16(MKKEY)
#undef MKKEY
#pragma unroll
        for (int r = 0; r < 4; ++r) {
            const int mm = 1 << r;
            const int W = 16 >> r;
            unsigned o_[16];
#pragma unroll
            for (int j = 0; j < W; ++j)
                o_[j] = (unsigned)__shfl_xor((int)k_[j], mm);
            const bool hi = (lane & mm) != 0;
#pragma unroll
            for (int j = 0; j < W / 2; ++j) {
                unsigned a = hi ? k_[j + W / 2] : k_[j];
                unsigned c = hi ? o_[j + W / 2] : o_[j];
                k_[j] = a > c ? a : c;
            }
        }
        {
            unsigned o = (unsigned)__shfl_xor((int)k_[0], 16);
            k_[0] = k_[0] > o ? k_[0] : o;
            o = (unsigned)__shfl_xor((int)k_[0], 32);
            k_[0] = k_[0] > o ? k_[0] : o;
        }
        if (lane < 16) {
            int p = ((lane & 1) << 3) | ((lane & 2) << 1) |
                    ((lane & 4) >> 1) | ((lane & 8) >> 3);
            keys[w][p] = k_[0];
        }
        __syncthreads();

        // ---- per-point row (16 threads; loads dominate) ----
        if (tid < 16) {
            unsigned key = keys[0][tid];
            unsigned k1 = keys[1][tid], k2 = keys[2][tid], k3 = keys[3][tid];
            key = key > k1 ? key : k1;
            key = key > k2 ? key : k2;
            key = key > k3 ? key : k3;
            int m = 4095 - (int)(key & 0xFFFu);
            float4 qq = ((const float4*)ptgt4)[(size_t)b * MPTS + m];
            const float* pp = psrc + ((size_t)b * NPTS + n0 + tid) * 3;
            float x = pp[0], y = pp[1], z = pp[2];
            float px = fmaf(R00, x, fmaf(R01, y, fmaf(R02, z, t0)));
            float py = fmaf(R10, x, fmaf(R11, y, fmaf(R12, z, t1)));
            float pz = fmaf(R20, x, fmaf(R21, y, fmaf(R22, z, t2)));
            float dx = px - qq.x, dy = py - qq.y, dz = pz - qq.z;
            float dist = sqrtf(dx * dx + dy * dy + dz * dz);
            red[tid][0] = px; red[tid][1] = py; red[tid][2] = pz;
            red[tid][3] = qq.x; red[tid][4] = qq.y; red[tid][5] = qq.z;
            red[tid][6] = px * qq.x;  red[tid][7] = px * qq.y;  red[tid][8] = px * qq.z;
            red[tid][9] = py * qq.x;  red[tid][10] = py * qq.y; red[tid][11] = py * qq.z;
            red[tid][12] = pz * qq.x; red[tid][13] = pz * qq.y; red[tid][14] = pz * qq.z;
            red[tid][15] = dist;
        }
        __syncthreads();
        // ---- parallel block-combine: 64 threads x 4-row quarters ----
        if (tid < 64) {
            int c = tid & 15, q = tid >> 4;
            rq[q][c] = ((red[4*q][c] + red[4*q+1][c]) + red[4*q+2][c]) + red[4*q+3][c];
        }
        __syncthreads();
        if (tid < 16) {
            float s = ((rq[0][tid] + rq[1][tid]) + rq[2][tid]) + rq[3][tid];
            __hip_atomic_store(&acc[((size_t)step * NBLK + bid) * 16 + tid], s,
                               __ATOMIC_RELAXED, __HIP_MEMORY_SCOPE_AGENT);
        }

        unsigned* stepc = ctrs + step * CTR_STRIDE;
        __syncthreads();   // drains the acc stores before arrival RMW

        if (step == NSTEPS - 1) {
            // ---- final step: workers arrive and exit; blocks 0 and 256
            // poll the master counter, gather own batch, solve, write out. ----
            if (tid == 0) {
                unsigned* sub = stepc + (bid & (NSUB - 1)) * 16;
                unsigned old = __hip_atomic_fetch_add(sub, 1u, __ATOMIC_RELAXED,
                                                      __HIP_MEMORY_SCOPE_AGENT);
                if (old == (unsigned)(NBLK / NSUB) - 1u)
                    __hip_atomic_fetch_add(stepc + 512, 1u, __ATOMIC_RELAXED,
                                           __HIP_MEMORY_SCOPE_AGENT);
            }
            if (bid != 0 && bid != 256) return;   // workers done
            if (tid == 0) {
                while (__hip_atomic_load(stepc + 512, __ATOMIC_RELAXED,
                                         __HIP_MEMORY_SCOPE_AGENT) < (unsigned)NSUB) {
                    __builtin_amdgcn_s_sleep(1);
                }
            }
            __syncthreads();
        } else {
            // ---- R9 barrier: sub RMW -> master RMW; global-last arriver
            // broadcasts 32 striped flags; everyone else polls its flag. ----
            if (tid == 0) {
                unsigned* sub = stepc + (bid & (NSUB - 1)) * 16;
                bool bcast = false;
                unsigned old = __hip_atomic_fetch_add(sub, 1u, __ATOMIC_RELAXED,
                                                      __HIP_MEMORY_SCOPE_AGENT);
                if (old == (unsigned)(NBLK / NSUB) - 1u) {
                    unsigned mold = __hip_atomic_fetch_add(stepc + 512, 1u,
                                        __ATOMIC_RELAXED, __HIP_MEMORY_SCOPE_AGENT);
                    if (mold == (unsigned)NSUB - 1u) {
#pragma unroll
                        for (int f = 0; f < NSUB; ++f)
                            __hip_atomic_store(stepc + 1024 + f * 16, 1u,
                                               __ATOMIC_RELAXED,
                                               __HIP_MEMORY_SCOPE_AGENT);
                        bcast = true;
                    }
                }
                if (!bcast) {
                    unsigned* myflag = stepc + 1024 + (bid & (NSUB - 1)) * 16;
                    while (__hip_atomic_load(myflag, __ATOMIC_RELAXED,
                                             __HIP_MEMORY_SCOPE_AGENT) == 0u) {
                        __builtin_amdgcn_s_sleep(1);
                    }
                }
            }
            __syncthreads();
        }

        // ---- per-batch gather: own 256 slots x 16 comps, 16 loads/thread;
        // tid>=192 concurrently sum the other batch's err column (4 loads).
        // Plain loads on fresh agent-stored region (pattern proven R8-R12). ----
        {
            const float* accs = acc + ((size_t)step * NBLK + b * 256) * 16;
            int c = tid & 15, g = tid >> 4;       // 16 groups x 16 slots
            float ssum = 0.f;
#pragma unroll
            for (int i = 0; i < 16; ++i)
                ssum += accs[(size_t)(g * 16 + i) * 16 + c];
            gred[g][c] = ssum;
        }
        if (tid >= 192) {
            const float* acco = acc + ((size_t)step * NBLK + (1 - b) * 256) * 16;
            int j = tid - 192;
            float s = ((acco[(size_t)(j*4+0)*16+15] + acco[(size_t)(j*4+1)*16+15])
                       + acco[(size_t)(j*4+2)*16+15]) + acco[(size_t)(j*4+3)*16+15];
            oerr[j] = s;
        }
        __syncthreads();
        if (tid < 64) {
            int c = tid & 15, q = tid >> 4;
            gq[q][c] = ((gred[4*q][c] + gred[4*q+1][c]) + gred[4*q+2][c]) + gred[4*q+3][c];
        } else if (tid >= 64 && tid < 72) {
            int j = tid - 64;
            float s = 0.f;
#pragma unroll
            for (int i = 0; i < 8; ++i) s += oerr[8*j + i];
            oe2[j] = s;
        }
        __syncthreads();
        if (tid < 16) {
            asumv[tid] = ((gq[0][tid] + gq[1][tid]) + gq[2][tid]) + gq[3][tid];
        } else if (tid == 16) {
            float s = 0.f;
#pragma unroll
            for (int i = 0; i < 8; ++i) s += oe2[i];
            oerrF = s;
        }
        __syncthreads();

        // ---- tid0: conv check + Horn solve + st update (one serial section) ----
        if (tid == 0) {
            const float inv_n = 1.f / NPTS;
            float errmy = asumv[15] * inv_n;
            float erro  = oerrF * inv_n;
            bool conv = (fabsf(errmy - st[b][12]) < ICP_TOL) &&
                        (fabsf(erro - oErrPrev) < ICP_TOL);
            contflag = conv ? 2 : 1;
            if (!conv) {
                float a[16];
                for (int i = 0; i < 16; ++i) a[i] = asumv[i];
                float pmx = a[0]*inv_n, pmy = a[1]*inv_n, pmz = a[2]*inv_n;
                float qmx = a[3]*inv_n, qmy = a[4]*inv_n, qmz = a[5]*inv_n;
                float H[3][3];
                for (int i = 0; i < 3; ++i)
                    for (int j = 0; j < 3; ++j)
                        H[i][j] = a[6 + 3*i + j] - a[i]*a[3 + j]*inv_n;
                float Sxx=H[0][0], Sxy=H[0][1], Sxz=H[0][2];
                float Syx=H[1][0], Syy=H[1][1], Syz=H[1][2];
                float Szx=H[2][0], Szy=H[2][1], Szz=H[2][2];
                float Nm[4][4];
                Nm[0][0] = Sxx+Syy+Szz; Nm[0][1] = Syz-Szy;
                Nm[0][2] = Szx-Sxz;     Nm[0][3] = Sxy-Syx;
                Nm[1][1] = Sxx-Syy-Szz; Nm[1][2] = Sxy+Syx; Nm[1][3] = Szx+Sxz;
                Nm[2][2] = -Sxx+Syy-Szz; Nm[2][3] = Syz+Szy;
                Nm[3][3] = -Sxx-Syy+Szz;
                Nm[1][0]=Nm[0][1]; Nm[2][0]=Nm[0][2]; Nm[3][0]=Nm[0][3];
                Nm[2][1]=Nm[1][2]; Nm[3][1]=Nm[1][3]; Nm[3][2]=Nm[2][3];
                float qv[4];
                horn_quat(Nm, qv);
                float qw = qv[0], qx = qv[1], qy = qv[2], qz = qv[3];
                float R00n = 1.f - 2.f*(qy*qy + qz*qz);
                float R01n = 2.f*(qx*qy - qw*qz);
                float R02n = 2.f*(qx*qz + qw*qy);
                float R10n = 2.f*(qx*qy + qw*qz);
                float R11n = 1.f - 2.f*(qx*qx + qz*qz);
                float R12n = 2.f*(qy*qz - qw*qx);
                float R20n = 2.f*(qx*qz - qw*qy);
                float R21n = 2.f*(qy*qz + qw*qx);
                float R22n = 1.f - 2.f*(qx*qx + qy*qy);
                float tx = qmx - (R00n*pmx + R01n*pmy + R02n*pmz);
                float ty = qmy - (R10n*pmx + R11n*pmy + R12n*pmz);
                float tz = qmz - (R20n*pmx + R21n*pmy + R22n*pmz);
                float C00=st[b][0], C01=st[b][1], C02=st[b][2];
                float C10=st[b][3], C11=st[b][4], C12=st[b][5];
                float C20=st[b][6], C21=st[b][7], C22=st[b][8];
                float T0=st[b][9], T1=st[b][10], T2=st[b][11];
                float ns[12];
                ns[0] = R00n*C00 + R01n*C10 + R02n*C20;
                ns[1] = R00n*C01 + R01n*C11 + R02n*C21;
                ns[2] = R00n*C02 + R01n*C12 + R02n*C22;
                ns[3] = R10n*C00 + R11n*C10 + R12n*C20;
                ns[4] = R10n*C01 + R11n*C11 + R12n*C21;
                ns[5] = R10n*C02 + R11n*C12 + R12n*C22;
                ns[6] = R20n*C00 + R21n*C10 + R22n*C20;
                ns[7] = R20n*C01 + R21n*C11 + R22n*C21;
                ns[8] = R20n*C02 + R21n*C12 + R22n*C22;
                ns[9]  = R00n*T0 + R01n*T1 + R02n*T2 + tx;
                ns[10] = R10n*T0 + R11n*T1 + R12n*T2 + ty;
                ns[11] = R20n*T0 + R21n*T1 + R22n*T2 + tz;
                for (int i = 0; i < 12; ++i) st[b][i] = ns[i];
                st[b][12] = errmy;
                oErrPrev = erro;
            }
        }
        __syncthreads();   // st/contflag visible before next step
        if (contflag == 2) break;   // uniform across surviving blocks
    }

    if ((bid == 0 || bid == 256) && tid == 0) {
        float r00 = st[b][0], r01 = st[b][1], r02 = st[b][2];
        float r10 = st[b][3], r11 = st[b][4], r12 = st[b][5];
        float r20 = st[b][6], r21 = st[b][7], r22 = st[b][8];
        float qw = 0.5f * sqrtf(fmaxf(1.f + r00 + r11 + r22, 1e-12f));
        float qx = 0.5f * sqrtf(fmaxf(1.f + r00 - r11 - r22, 1e-12f));
        float qy = 0.5f * sqrtf(fmaxf(1.f - r00 + r11 - r22, 1e-12f));
        float qz = 0.5f * sqrtf(fmaxf(1.f - r00 - r11 + r22, 1e-12f));
        qx = (r21 - r12 >= 0.f) ? qx : -qx;
        qy = (r02 - r20 >= 0.f) ? qy : -qy;
        qz = (r10 - r01 >= 0.f) ? qz : -qz;
        out[b * 7 + 0] = st[b][9];
        out[b * 7 + 1] = st[b][10];
        out[b * 7 + 2] = st[b][11];
        out[b * 7 + 3] = qx;
        out[b * 7 + 4] = qy;
        out[b * 7 + 5] = qz;
        out[b * 7 + 6] = qw;
    }
}

extern "C" void kernel_launch(void* const* d_in, const int* in_sizes, int n_in,
                              void* d_out, int out_size, void* d_ws, size_t ws_size,
                              hipStream_t stream) {
    const float* psrc = (const float*)d_in[0];
    const float* ptgt = (const float*)d_in[1];
    float* out = (float*)d_out;
    float* ws = (float*)d_ws;

    init_kernel<<<32, 256, 0, stream>>>(ptgt, ws);
    icp_main<<<NBLK, 256, 0, stream>>>(psrc, ws, out);
}

// Round 6
// 179.743 us; speedup vs baseline: 1.0006x; 1.0006x over previous
//
#include <hip/hip_runtime.h>
#include <math.h>

#define NPTS 4096
#define MPTS 4096
#define NSTEPS 8
#define ICP_TOL 1e-6f
#define NBLK 512    // 2 blocks/CU @ launch_bounds(256,2): proven resident (R5-R12)
#define NSUB 32     // arrival sub-counters, 16 blocks each

// ws layout (floats):
//   ptgt4 : [0, 32768)         interleaved {x,y,z,0.5*|t|^2}, 2*4096 targets
//   acc   : [32768, 98304)     [step][block(512)][16] per-block partials (atomic stores)
//   ctrs  : words at 98304, 1536/step: subs at c*16 (c<32), master at 512,
//           flags at 1024+f*16 (f<32); value 0=wait, 1=released
#define ACC_OFF 32768
#define CTR_OFF 98304
#define CTR_STRIDE 1536

__global__ void init_kernel(const float* __restrict__ ptgt, float* __restrict__ ws) {
    float* ptgt4 = ws;
    unsigned* ctrs = (unsigned*)(ws + CTR_OFF);
    int gid = blockIdx.x * 256 + threadIdx.x;   // 8192 threads
    if (gid < 2 * MPTS) {
        float x = ptgt[3 * gid + 0];
        float y = ptgt[3 * gid + 1];
        float z = ptgt[3 * gid + 2];
        float4 v;
        v.x = x; v.y = y; v.z = z;
        v.w = 0.5f * (x * x + y * y + z * z);
        ((float4*)ptgt4)[gid] = v;
    }
    for (int i = gid; i < NSTEPS * CTR_STRIDE; i += 8192) ctrs[i] = 0u;
}

__device__ __forceinline__ float frcp(float x) {
#if __has_builtin(__builtin_amdgcn_rcpf)
    return __builtin_amdgcn_rcpf(x);
#else
    return 1.f / x;
#endif
}
__device__ __forceinline__ float frsq(float x) {
#if __has_builtin(__builtin_amdgcn_rsqf)
    return __builtin_amdgcn_rsqf(x);
#else
    return 1.f / sqrtf(x);
#endif
}

#define DET3(a,b,c,d,e,f,g,h,i) \
    ((a)*((e)*(i)-(f)*(h)) - (b)*((d)*(i)-(f)*(g)) + (c)*((d)*(h)-(e)*(g)))

// Max-eigenpair of symmetric 4x4 via Newton on the characteristic quartic
// (monotone from Gershgorin upper bound) + cofactor-row eigenvector.
// 8 Newton iterations (quadratic convergence; rel err < 1e-12 by 8).
__device__ __forceinline__ void horn_quat(const float N[4][4], float q[4]) {
    float s = 1e-30f;
#pragma unroll
    for (int i = 0; i < 4; ++i)
#pragma unroll
        for (int j = 0; j < 4; ++j) s = fmaxf(s, fabsf(N[i][j]));
    float inv = frcp(s);
    float A[4][4], B[4][4];
#pragma unroll
    for (int i = 0; i < 4; ++i)
#pragma unroll
        for (int j = 0; j < 4; ++j) A[i][j] = N[i][j] * inv;
#pragma unroll
    for (int i = 0; i < 4; ++i)
#pragma unroll
        for (int j = i; j < 4; ++j) {
            float v = A[i][0]*A[0][j] + A[i][1]*A[1][j] + A[i][2]*A[2][j] + A[i][3]*A[3][j];
            B[i][j] = v; B[j][i] = v;
        }
    float p1 = A[0][0]+A[1][1]+A[2][2]+A[3][3];
    float p2 = B[0][0]+B[1][1]+B[2][2]+B[3][3];
    float p3 = 0.f, p4 = 0.f;
#pragma unroll
    for (int i = 0; i < 4; ++i)
#pragma unroll
        for (int j = 0; j < 4; ++j) { p3 += A[i][j]*B[i][j]; p4 += B[i][j]*B[i][j]; }
    float e1 = p1;
    float e2 = 0.5f*(e1*p1 - p2);
    float e3 = (e2*p1 - e1*p2 + p3)*(1.f/3.f);
    float e4 = 0.25f*(e3*p1 - e2*p2 + e1*p3 - p4);
    float lam = -3e38f;
#pragma unroll
    for (int i = 0; i < 4; ++i) {
        float r = A[i][i];
#pragma unroll
        for (int j = 0; j < 4; ++j) if (j != i) r += fabsf(A[i][j]);
        lam = fmaxf(lam, r);
    }
#pragma unroll
    for (int it = 0; it < 8; ++it) {
        float pv = (((lam - e1)*lam + e2)*lam - e3)*lam + e4;
        float dv = ((4.f*lam - 3.f*e1)*lam + 2.f*e2)*lam - e3;
        lam -= pv * frcp(dv);
    }
    float M[4][4];
#pragma unroll
    for (int i = 0; i < 4; ++i)
#pragma unroll
        for (int j = 0; j < 4; ++j) M[i][j] = A[i][j] - ((i == j) ? lam : 0.f);
    float C0 = DET3(M[1][1],M[1][2],M[1][3], M[2][1],M[2][2],M[2][3], M[3][1],M[3][2],M[3][3]);
    float C1 = DET3(M[0][0],M[0][2],M[0][3], M[2][0],M[2][2],M[2][3], M[3][0],M[3][2],M[3][3]);
    float C2 = DET3(M[0][0],M[0][1],M[0][3], M[1][0],M[1][1],M[1][3], M[3][0],M[3][1],M[3][3]);
    float C3 = DET3(M[0][0],M[0][1],M[0][2], M[1][0],M[1][1],M[1][2], M[2][0],M[2][1],M[2][2]);
    int is = 0; float cb = fabsf(C0);
    if (fabsf(C1) > cb) { cb = fabsf(C1); is = 1; }
    if (fabsf(C2) > cb) { cb = fabsf(C2); is = 2; }
    if (fabsf(C3) > cb) { cb = fabsf(C3); is = 3; }
    float v0, v1, v2, v3;
#define ROWCOF(a,b,c) { \
    v0 =  DET3(M[a][1],M[a][2],M[a][3], M[b][1],M[b][2],M[b][3], M[c][1],M[c][2],M[c][3]); \
    v1 = -DET3(M[a][0],M[a][2],M[a][3], M[b][0],M[b][2],M[b][3], M[c][0],M[c][2],M[c][3]); \
    v2 =  DET3(M[a][0],M[a][1],M[a][3], M[b][0],M[b][1],M[b][3], M[c][0],M[c][1],M[c][3]); \
    v3 = -DET3(M[a][0],M[a][1],M[a][2], M[b][0],M[b][1],M[b][2], M[c][0],M[c][1],M[c][2]); }
    if (is == 0)      ROWCOF(1,2,3)
    else if (is == 1) ROWCOF(0,2,3)
    else if (is == 2) ROWCOF(0,1,3)
    else              ROWCOF(0,1,2)
#undef ROWCOF
    float nr = frsq(v0*v0 + v1*v1 + v2*v2 + v3*v3);
    q[0] = v0*nr; q[1] = v1*nr; q[2] = v2*nr; q[3] = v3*nr;
}

#define FOR16(OP) OP(0) OP(1) OP(2) OP(3) OP(4) OP(5) OP(6) OP(7) \
                  OP(8) OP(9) OP(10) OP(11) OP(12) OP(13) OP(14) OP(15)

// 512 blocks x 256 threads, persistent (2 blocks/CU). R14 = R12's NN/argmax/
// combine body (VGPR-fit proven: in-loop ps loads, depth-2 prefetch, serial
// tid<16 block-combine — R13's hoist/depth-3/parallel-combine spilled the
// 128-VGPR budget and cost +18us in the inner loop) + R13's cheaper tail:
// per-batch gather (16 loads/thread own batch; tid>=192 sum other batch's
// err column), 2-level tree, fused tid0 conv+solve (Horn, 8 Newton its).
// Final step: workers return after arrival RMW; blocks 0 AND 256 poll master,
// gather, solve, write their batch's out row. R9 counter barrier topology
// (1 poller/block). Fence-free visibility pattern proven R5-R12.
__global__ __launch_bounds__(256, 2) void icp_main(
    const float* __restrict__ psrc, float* __restrict__ ws,
    float* __restrict__ out) {

    float* ptgt4 = ws;
    float* acc = ws + ACC_OFF;
    unsigned* ctrs = (unsigned*)(ws + CTR_OFF);

    __shared__ float st[2][13];     // own batch row used: Rcum(9), tcum(3), err(1)
    __shared__ unsigned keys[4][16];
    __shared__ float red[16][16];
    __shared__ float gred[16][16];  // gather partials [group][comp]
    __shared__ float gq[4][16];     // gather quarter partials
    __shared__ float oerr[64];      // other-batch err partials
    __shared__ float oe2[8];
    __shared__ float asumv[16];     // own-batch totals
    __shared__ float oerrF;         // other-batch err total
    __shared__ float oErrPrev;      // other-batch previous err
    __shared__ int contflag;        // 1=continue, 2=done

    const int tid = threadIdx.x;
    const int bid = blockIdx.x;
    const int b = bid >> 8;             // batch (256 blocks each)
    const int n0 = (bid & 255) * 16;    // this block's 16 source points

    if (tid == 0) {
        st[b][0] = 1.f; st[b][1] = 0.f; st[b][2] = 0.f;
        st[b][3] = 0.f; st[b][4] = 1.f; st[b][5] = 0.f;
        st[b][6] = 0.f; st[b][7] = 0.f; st[b][8] = 1.f;
        st[b][9] = 0.f; st[b][10] = 0.f; st[b][11] = 0.f;
        st[b][12] = 0.f;
        oErrPrev = 0.f;
    }
    __syncthreads();

    const int w = tid >> 6, lane = tid & 63;
    const int m0 = w * 1024 + lane;
    const float4* tpb = (const float4*)ptgt4 + ((size_t)b * MPTS + m0);
    const float* ps = psrc + ((size_t)b * NPTS + n0) * 3;

    for (int step = 0; step < NSTEPS; ++step) {
        float R00 = st[b][0], R01 = st[b][1], R02 = st[b][2];
        float R10 = st[b][3], R11 = st[b][4], R12 = st[b][5];
        float R20 = st[b][6], R21 = st[b][7], R22 = st[b][8];
        float t0 = st[b][9], t1 = st[b][10], t2 = st[b][11];

#define DECLP(i) float px##i, py##i, pz##i;
        FOR16(DECLP)
#undef DECLP
#define LOADP(i) { float x = ps[3*(i)], y = ps[3*(i)+1], z = ps[3*(i)+2]; \
        px##i = fmaf(R00, x, fmaf(R01, y, fmaf(R02, z, t0))); \
        py##i = fmaf(R10, x, fmaf(R11, y, fmaf(R12, z, t1))); \
        pz##i = fmaf(R20, x, fmaf(R21, y, fmaf(R22, z, t2))); }
        FOR16(LOADP)
#undef LOADP

        // s = p.t - |t|^2/2; argmax s == argmin dist (strict > keeps first max)
#define DECLB(i) float bs##i = -3.0e38f; int ix##i = m0;
        FOR16(DECLB)
#undef DECLB

        float4 tc0 = tpb[0];
        float4 tc1 = tpb[64];
        int mreg = m0;
#pragma unroll
        for (int k = 0; k < 16; ++k) {
            float4 tnx = tpb[((k + 2) & 15) * 64];  // wraps harmlessly
            float tx = tc0.x, ty = tc0.y, tz = tc0.z, htn = tc0.w;
#define PAIR(i) { float s = fmaf(px##i, tx, fmaf(py##i, ty, fmaf(pz##i, tz, -htn))); \
            if (s > bs##i) { bs##i = s; ix##i = mreg; } }
            FOR16(PAIR)
#undef PAIR
            mreg += 64;
            tc0 = tc1;
            tc1 = tnx;
        }

        // ---- wave argmax: order-preserving packed key (score hi-20 |
        // 4095-m), payload-halving fold butterfly (32 shuffles, HW-verified
        // bitwise == 96-shuffle tree, R11/R12). ----
        unsigned k_[16];
#define MKKEY(i) { unsigned ub = __float_as_uint(bs##i); \
        unsigned u = ((int)ub >= 0) ? (ub | 0x80000000u) : ~ub; \
        k_[i] = (u & 0xFFFFF000u) | (4095u - (unsigned)ix##i); }
        FOR16(MKKEY)
#undef MKKEY
#pragma unroll
        for (int r = 0; r < 4; ++r) {
            const int mm = 1 << r;
            const int W = 16 >> r;
            unsigned o_[16];
#pragma unroll
            for (int j = 0; j < W; ++j)
                o_[j] = (unsigned)__shfl_xor((int)k_[j], mm);
            const bool hi = (lane & mm) != 0;
#pragma unroll
            for (int j = 0; j < W / 2; ++j) {
                unsigned a = hi ? k_[j + W / 2] : k_[j];
                unsigned c = hi ? o_[j + W / 2] : o_[j];
                k_[j] = a > c ? a : c;
            }
        }
        {
            unsigned o = (unsigned)__shfl_xor((int)k_[0], 16);
            k_[0] = k_[0] > o ? k_[0] : o;
            o = (unsigned)__shfl_xor((int)k_[0], 32);
            k_[0] = k_[0] > o ? k_[0] : o;
        }
        if (lane < 16) {
            int p = ((lane & 1) << 3) | ((lane & 2) << 1) |
                    ((lane & 4) >> 1) | ((lane & 8) >> 3);
            keys[w][p] = k_[0];
        }
        __syncthreads();

        // ---- block-combine + per-point row + serial partial sum + acc
        // store: all in wave 0, lanes 0-15 (R12 body; same-wave LDS ordered
        // via lgkmcnt, no extra barriers). ----
        if (tid < 16) {
            unsigned key = keys[0][tid];
            unsigned k1 = keys[1][tid], k2 = keys[2][tid], k3 = keys[3][tid];
            key = key > k1 ? key : k1;
            key = key > k2 ? key : k2;
            key = key > k3 ? key : k3;
            int m = 4095 - (int)(key & 0xFFFu);
            float4 qq = ((const float4*)ptgt4)[(size_t)b * MPTS + m];
            const float* pp = psrc + ((size_t)b * NPTS + n0 + tid) * 3;
            float x = pp[0], y = pp[1], z = pp[2];
            float px = fmaf(R00, x, fmaf(R01, y, fmaf(R02, z, t0)));
            float py = fmaf(R10, x, fmaf(R11, y, fmaf(R12, z, t1)));
            float pz = fmaf(R20, x, fmaf(R21, y, fmaf(R22, z, t2)));
            float dx = px - qq.x, dy = py - qq.y, dz = pz - qq.z;
            float dist = sqrtf(dx * dx + dy * dy + dz * dz);
            red[tid][0] = px; red[tid][1] = py; red[tid][2] = pz;
            red[tid][3] = qq.x; red[tid][4] = qq.y; red[tid][5] = qq.z;
            red[tid][6] = px * qq.x;  red[tid][7] = px * qq.y;  red[tid][8] = px * qq.z;
            red[tid][9] = py * qq.x;  red[tid][10] = py * qq.y; red[tid][11] = py * qq.z;
            red[tid][12] = pz * qq.x; red[tid][13] = pz * qq.y; red[tid][14] = pz * qq.z;
            red[tid][15] = dist;
            float s = 0.f;
#pragma unroll
            for (int r = 0; r < 16; ++r) s += red[r][tid];
            __hip_atomic_store(&acc[((size_t)step * NBLK + bid) * 16 + tid], s,
                               __ATOMIC_RELAXED, __HIP_MEMORY_SCOPE_AGENT);
        }

        unsigned* stepc = ctrs + step * CTR_STRIDE;
        __syncthreads();   // drains the acc stores before arrival RMW

        if (step == NSTEPS - 1) {
            // ---- final step: workers arrive and exit; blocks 0 and 256
            // poll the master counter, gather own batch, solve, write out. ----
            if (tid == 0) {
                unsigned* sub = stepc + (bid & (NSUB - 1)) * 16;
                unsigned old = __hip_atomic_fetch_add(sub, 1u, __ATOMIC_RELAXED,
                                                      __HIP_MEMORY_SCOPE_AGENT);
                if (old == (unsigned)(NBLK / NSUB) - 1u)
                    __hip_atomic_fetch_add(stepc + 512, 1u, __ATOMIC_RELAXED,
                                           __HIP_MEMORY_SCOPE_AGENT);
            }
            if (bid != 0 && bid != 256) return;   // workers done
            if (tid == 0) {
                while (__hip_atomic_load(stepc + 512, __ATOMIC_RELAXED,
                                         __HIP_MEMORY_SCOPE_AGENT) < (unsigned)NSUB) {
                    __builtin_amdgcn_s_sleep(1);
                }
            }
            __syncthreads();
        } else {
            // ---- R9 barrier: sub RMW -> master RMW; global-last arriver
            // broadcasts 32 striped flags; everyone else polls its flag. ----
            if (tid == 0) {
                unsigned* sub = stepc + (bid & (NSUB - 1)) * 16;
                bool bcast = false;
                unsigned old = __hip_atomic_fetch_add(sub, 1u, __ATOMIC_RELAXED,
                                                      __HIP_MEMORY_SCOPE_AGENT);
                if (old == (unsigned)(NBLK / NSUB) - 1u) {
                    unsigned mold = __hip_atomic_fetch_add(stepc + 512, 1u,
                                        __ATOMIC_RELAXED, __HIP_MEMORY_SCOPE_AGENT);
                    if (mold == (unsigned)NSUB - 1u) {
#pragma unroll
                        for (int f = 0; f < NSUB; ++f)
                            __hip_atomic_store(stepc + 1024 + f * 16, 1u,
                                               __ATOMIC_RELAXED,
                                               __HIP_MEMORY_SCOPE_AGENT);
                        bcast = true;
                    }
                }
                if (!bcast) {
                    unsigned* myflag = stepc + 1024 + (bid & (NSUB - 1)) * 16;
                    while (__hip_atomic_load(myflag, __ATOMIC_RELAXED,
                                             __HIP_MEMORY_SCOPE_AGENT) == 0u) {
                        __builtin_amdgcn_s_sleep(1);
                    }
                }
            }
            __syncthreads();
        }

        // ---- per-batch gather: own 256 slots x 16 comps, 16 loads/thread;
        // tid>=192 concurrently sum the other batch's err column (4 loads).
        // Plain loads on fresh agent-stored region (pattern proven R8-R13). ----
        {
            const float* accs = acc + ((size_t)step * NBLK + b * 256) * 16;
            int c = tid & 15, g = tid >> 4;       // 16 groups x 16 slots
            float ssum = 0.f;
#pragma unroll
            for (int i = 0; i < 16; ++i)
                ssum += accs[(size_t)(g * 16 + i) * 16 + c];
            gred[g][c] = ssum;
        }
        if (tid >= 192) {
            const float* acco = acc + ((size_t)step * NBLK + (1 - b) * 256) * 16;
            int j = tid - 192;
            float s = ((acco[(size_t)(j*4+0)*16+15] + acco[(size_t)(j*4+1)*16+15])
                       + acco[(size_t)(j*4+2)*16+15]) + acco[(size_t)(j*4+3)*16+15];
            oerr[j] = s;
        }
        __syncthreads();
        if (tid < 64) {
            int c = tid & 15, q = tid >> 4;
            gq[q][c] = ((gred[4*q][c] + gred[4*q+1][c]) + gred[4*q+2][c]) + gred[4*q+3][c];
        } else if (tid >= 64 && tid < 72) {
            int j = tid - 64;
            float s = 0.f;
#pragma unroll
            for (int i = 0; i < 8; ++i) s += oerr[8*j + i];
            oe2[j] = s;
        }
        __syncthreads();
        if (tid < 16) {
            asumv[tid] = ((gq[0][tid] + gq[1][tid]) + gq[2][tid]) + gq[3][tid];
        } else if (tid == 16) {
            float s = 0.f;
#pragma unroll
            for (int i = 0; i < 8; ++i) s += oe2[i];
            oerrF = s;
        }
        __syncthreads();

        // ---- tid0: conv check + Horn solve + st update (one serial section) ----
        if (tid == 0) {
            const float inv_n = 1.f / NPTS;
            float errmy = asumv[15] * inv_n;
            float erro  = oerrF * inv_n;
            bool conv = (fabsf(errmy - st[b][12]) < ICP_TOL) &&
                        (fabsf(erro - oErrPrev) < ICP_TOL);
            contflag = conv ? 2 : 1;
            if (!conv) {
                float a[16];
                for (int i = 0; i < 16; ++i) a[i] = asumv[i];
                float pmx = a[0]*inv_n, pmy = a[1]*inv_n, pmz = a[2]*inv_n;
                float qmx = a[3]*inv_n, qmy = a[4]*inv_n, qmz = a[5]*inv_n;
                float H[3][3];
                for (int i = 0; i < 3; ++i)
                    for (int j = 0; j < 3; ++j)
                        H[i][j] = a[6 + 3*i + j] - a[i]*a[3 + j]*inv_n;
                float Sxx=H[0][0], Sxy=H[0][1], Sxz=H[0][2];
                float Syx=H[1][0], Syy=H[1][1], Syz=H[1][2];
                float Szx=H[2][0], Szy=H[2][1], Szz=H[2][2];
                float Nm[4][4];
                Nm[0][0] = Sxx+Syy+Szz; Nm[0][1] = Syz-Szy;
                Nm[0][2] = Szx-Sxz;     Nm[0][3] = Sxy-Syx;
                Nm[1][1] = Sxx-Syy-Szz; Nm[1][2] = Sxy+Syx; Nm[1][3] = Szx+Sxz;
                Nm[2][2] = -Sxx+Syy-Szz; Nm[2][3] = Syz+Szy;
                Nm[3][3] = -Sxx-Syy+Szz;
                Nm[1][0]=Nm[0][1]; Nm[2][0]=Nm[0][2]; Nm[3][0]=Nm[0][3];
                Nm[2][1]=Nm[1][2]; Nm[3][1]=Nm[1][3]; Nm[3][2]=Nm[2][3];
                float qv[4];
                horn_quat(Nm, qv);
                float qw = qv[0], qx = qv[1], qy = qv[2], qz = qv[3];
                float R00n = 1.f - 2.f*(qy*qy + qz*qz);
                float R01n = 2.f*(qx*qy - qw*qz);
                float R02n = 2.f*(qx*qz + qw*qy);
                float R10n = 2.f*(qx*qy + qw*qz);
                float R11n = 1.f - 2.f*(qx*qx + qz*qz);
                float R12n = 2.f*(qy*qz - qw*qx);
                float R20n = 2.f*(qx*qz - qw*qy);
                float R21n = 2.f*(qy*qz + qw*qx);
                float R22n = 1.f - 2.f*(qx*qx + qy*qy);
                float tx = qmx - (R00n*pmx + R01n*pmy + R02n*pmz);
                float ty = qmy - (R10n*pmx + R11n*pmy + R12n*pmz);
                float tz = qmz - (R20n*pmx + R21n*pmy + R22n*pmz);
                float C00=st[b][0], C01=st[b][1], C02=st[b][2];
                float C10=st[b][3], C11=st[b][4], C12=st[b][5];
                float C20=st[b][6], C21=st[b][7], C22=st[b][8];
                float T0=st[b][9], T1=st[b][10], T2=st[b][11];
                float ns[12];
                ns[0] = R00n*C00 + R01n*C10 + R02n*C20;
                ns[1] = R00n*C01 + R01n*C11 + R02n*C21;
                ns[2] = R00n*C02 + R01n*C12 + R02n*C22;
                ns[3] = R10n*C00 + R11n*C10 + R12n*C20;
                ns[4] = R10n*C01 + R11n*C11 + R12n*C21;
                ns[5] = R10n*C02 + R11n*C12 + R12n*C22;
                ns[6] = R20n*C00 + R21n*C10 + R22n*C20;
                ns[7] = R20n*C01 + R21n*C11 + R22n*C21;
                ns[8] = R20n*C02 + R21n*C12 + R22n*C22;
                ns[9]  = R00n*T0 + R01n*T1 + R02n*T2 + tx;
                ns[10] = R10n*T0 + R11n*T1 + R12n*T2 + ty;
                ns[11] = R20n*T0 + R21n*T1 + R22n*T2 + tz;
                for (int i = 0; i < 12; ++i) st[b][i] = ns[i];
                st[b][12] = errmy;
                oErrPrev = erro;
            }
        }
        __syncthreads();   // st/contflag visible before next step
        if (contflag == 2) break;   // uniform across surviving blocks
    }

    if ((bid == 0 || bid == 256) && tid == 0) {
        float r00 = st[b][0], r01 = st[b][1], r02 = st[b][2];
        float r10 = st[b][3], r11 = st[b][4], r12 = st[b][5];
        float r20 = st[b][6], r21 = st[b][7], r22 = st[b][8];
        float qw = 0.5f * sqrtf(fmaxf(1.f + r00 + r11 + r22, 1e-12f));
        float qx = 0.5f * sqrtf(fmaxf(1.f + r00 - r11 - r22, 1e-12f));
        float qy = 0.5f * sqrtf(fmaxf(1.f - r00 + r11 - r22, 1e-12f));
        float qz = 0.5f * sqrtf(fmaxf(1.f - r00 - r11 + r22, 1e-12f));
        qx = (r21 - r12 >= 0.f) ? qx : -qx;
        qy = (r02 - r20 >= 0.f) ? qy : -qy;
        qz = (r10 - r01 >= 0.f) ? qz : -qz;
        out[b * 7 + 0] = st[b][9];
        out[b * 7 + 1] = st[b][10];
        out[b * 7 + 2] = st[b][11];
        out[b * 7 + 3] = qx;
        out[b * 7 + 4] = qy;
        out[b * 7 + 5] = qz;
        out[b * 7 + 6] = qw;
    }
}

extern "C" void kernel_launch(void* const* d_in, const int* in_sizes, int n_in,
                              void* d_out, int out_size, void* d_ws, size_t ws_size,
                              hipStream_t stream) {
    const float* psrc = (const float*)d_in[0];
    const float* ptgt = (const float*)d_in[1];
    float* out = (float*)d_out;
    float* ws = (float*)d_ws;

    init_kernel<<<32, 256, 0, stream>>>(ptgt, ws);
    icp_main<<<NBLK, 256, 0, stream>>>(psrc, ws, out);
}

// Round 9
// 161.002 us; speedup vs baseline: 1.1171x; 1.1164x over previous
//
#include <hip/hip_runtime.h>
#include <math.h>

#define NPTS 4096
#define MPTS 4096
#define NSTEPS 8
#define ICP_TOL 1e-6f
#define NBLK 512    // 2 blocks/CU @ launch_bounds(256,2): proven resident, no spill (R5-R8)
#define NSUB 32     // arrival sub-counters, 16 blocks each

// ws layout (floats):
//   ptgt4 : [0, 32768)         interleaved {x,y,z,0.5*|t|^2}, 2*4096 targets
//   acc   : [32768, 98304)     [step][block(512)][16] per-block partials (atomic stores)
//   ctrs  : words at 98304, 1536/step: subs at c*16 (c<32), master at 512,
//           flags at 1024+f*16 (f<32); value 0=wait, 1=released
#define ACC_OFF 32768
#define CTR_OFF 98304
#define CTR_STRIDE 1536

__global__ void init_kernel(const float* __restrict__ ptgt, float* __restrict__ ws) {
    float* ptgt4 = ws;
    unsigned* ctrs = (unsigned*)(ws + CTR_OFF);
    int gid = blockIdx.x * 256 + threadIdx.x;   // 8192 threads
    if (gid < 2 * MPTS) {
        float x = ptgt[3 * gid + 0];
        float y = ptgt[3 * gid + 1];
        float z = ptgt[3 * gid + 2];
        float4 v;
        v.x = x; v.y = y; v.z = z;
        v.w = 0.5f * (x * x + y * y + z * z);
        ((float4*)ptgt4)[gid] = v;
    }
    for (int i = gid; i < NSTEPS * CTR_STRIDE; i += 8192) ctrs[i] = 0u;
}

__device__ __forceinline__ float frcp(float x) {
#if __has_builtin(__builtin_amdgcn_rcpf)
    return __builtin_amdgcn_rcpf(x);
#else
    return 1.f / x;
#endif
}
__device__ __forceinline__ float frsq(float x) {
#if __has_builtin(__builtin_amdgcn_rsqf)
    return __builtin_amdgcn_rsqf(x);
#else
    return 1.f / sqrtf(x);
#endif
}

#define DET3(a,b,c,d,e,f,g,h,i) \
    ((a)*((e)*(i)-(f)*(h)) - (b)*((d)*(i)-(f)*(g)) + (c)*((d)*(h)-(e)*(g)))

// Max-eigenpair of symmetric 4x4 via Newton on the characteristic quartic
// (monotone from Gershgorin upper bound) + cofactor-row eigenvector.
__device__ __forceinline__ void horn_quat(const float N[4][4], float q[4]) {
    float s = 1e-30f;
#pragma unroll
    for (int i = 0; i < 4; ++i)
#pragma unroll
        for (int j = 0; j < 4; ++j) s = fmaxf(s, fabsf(N[i][j]));
    float inv = frcp(s);
    float A[4][4], B[4][4];
#pragma unroll
    for (int i = 0; i < 4; ++i)
#pragma unroll
        for (int j = 0; j < 4; ++j) A[i][j] = N[i][j] * inv;
#pragma unroll
    for (int i = 0; i < 4; ++i)
#pragma unroll
        for (int j = i; j < 4; ++j) {
            float v = A[i][0]*A[0][j] + A[i][1]*A[1][j] + A[i][2]*A[2][j] + A[i][3]*A[3][j];
            B[i][j] = v; B[j][i] = v;
        }
    float p1 = A[0][0]+A[1][1]+A[2][2]+A[3][3];
    float p2 = B[0][0]+B[1][1]+B[2][2]+B[3][3];
    float p3 = 0.f, p4 = 0.f;
#pragma unroll
    for (int i = 0; i < 4; ++i)
#pragma unroll
        for (int j = 0; j < 4; ++j) { p3 += A[i][j]*B[i][j]; p4 += B[i][j]*B[i][j]; }
    float e1 = p1;
    float e2 = 0.5f*(e1*p1 - p2);
    float e3 = (e2*p1 - e1*p2 + p3)*(1.f/3.f);
    float e4 = 0.25f*(e3*p1 - e2*p2 + e1*p3 - p4);
    float lam = -3e38f;
#pragma unroll
    for (int i = 0; i < 4; ++i) {
        float r = A[i][i];
#pragma unroll
        for (int j = 0; j < 4; ++j) if (j != i) r += fabsf(A[i][j]);
        lam = fmaxf(lam, r);
    }
#pragma unroll
    for (int it = 0; it < 12; ++it) {
        float pv = (((lam - e1)*lam + e2)*lam - e3)*lam + e4;
        float dv = ((4.f*lam - 3.f*e1)*lam + 2.f*e2)*lam - e3;
        lam -= pv * frcp(dv);
    }
    float M[4][4];
#pragma unroll
    for (int i = 0; i < 4; ++i)
#pragma unroll
        for (int j = 0; j < 4; ++j) M[i][j] = A[i][j] - ((i == j) ? lam : 0.f);
    float C0 = DET3(M[1][1],M[1][2],M[1][3], M[2][1],M[2][2],M[2][3], M[3][1],M[3][2],M[3][3]);
    float C1 = DET3(M[0][0],M[0][2],M[0][3], M[2][0],M[2][2],M[2][3], M[3][0],M[3][2],M[3][3]);
    float C2 = DET3(M[0][0],M[0][1],M[0][3], M[1][0],M[1][1],M[1][3], M[3][0],M[3][1],M[3][3]);
    float C3 = DET3(M[0][0],M[0][1],M[0][2], M[1][0],M[1][1],M[1][2], M[2][0],M[2][1],M[2][2]);
    int is = 0; float cb = fabsf(C0);
    if (fabsf(C1) > cb) { cb = fabsf(C1); is = 1; }
    if (fabsf(C2) > cb) { cb = fabsf(C2); is = 2; }
    if (fabsf(C3) > cb) { cb = fabsf(C3); is = 3; }
    float v0, v1, v2, v3;
#define ROWCOF(a,b,c) { \
    v0 =  DET3(M[a][1],M[a][2],M[a][3], M[b][1],M[b][2],M[b][3], M[c][1],M[c][2],M[c][3]); \
    v1 = -DET3(M[a][0],M[a][2],M[a][3], M[b][0],M[b][2],M[b][3], M[c][0],M[c][2],M[c][3]); \
    v2 =  DET3(M[a][0],M[a][1],M[a][3], M[b][0],M[b][1],M[b][3], M[c][0],M[c][1],M[c][3]); \
    v3 = -DET3(M[a][0],M[a][1],M[a][2], M[b][0],M[b][1],M[b][2], M[c][0],M[c][1],M[c][2]); }
    if (is == 0)      ROWCOF(1,2,3)
    else if (is == 1) ROWCOF(0,2,3)
    else if (is == 2) ROWCOF(0,1,3)
    else              ROWCOF(0,1,2)
#undef ROWCOF
    float nr = frsq(v0*v0 + v1*v1 + v2*v2 + v3*v3);
    q[0] = v0*nr; q[1] = v1*nr; q[2] = v2*nr; q[3] = v3*nr;
}

#define FOR16(OP) OP(0) OP(1) OP(2) OP(3) OP(4) OP(5) OP(6) OP(7) \
                  OP(8) OP(9) OP(10) OP(11) OP(12) OP(13) OP(14) OP(15)

// R17 = byte-exact resubmission of R12 (passed Round 4: 159.8us bench /
// ~114us kernel) as an infra-isolation control after R15/R16 failed twice
// with "container failed twice" and no profile. R16 had all polls bounded,
// so a kernel-side hang is excluded; a known-good binary failing again
// would prove the environment is the problem. No source changes vs R12.
__global__ __launch_bounds__(256, 2) void icp_main(
    const float* __restrict__ psrc, float* __restrict__ ws,
    float* __restrict__ out) {

    float* ptgt4 = ws;
    float* acc = ws + ACC_OFF;
    unsigned* ctrs = (unsigned*)(ws + CTR_OFF);

    __shared__ float st[2][13];     // per batch: Rcum(9), tcum(3), err(1)
    __shared__ unsigned keys[4][16];
    __shared__ float red[16][16];
    __shared__ float gred[16][16];  // gather partials [group][comp]
    __shared__ float asum[2][16];
    __shared__ int contflag;        // 1=continue, 2=done

    const int tid = threadIdx.x;
    const int bid = blockIdx.x;
    const int b = bid >> 8;             // batch (256 blocks each)
    const int n0 = (bid & 255) * 16;    // this block's 16 source points

    if (tid < 2) {
        st[tid][0] = 1.f; st[tid][1] = 0.f; st[tid][2] = 0.f;
        st[tid][3] = 0.f; st[tid][4] = 1.f; st[tid][5] = 0.f;
        st[tid][6] = 0.f; st[tid][7] = 0.f; st[tid][8] = 1.f;
        st[tid][9] = 0.f; st[tid][10] = 0.f; st[tid][11] = 0.f;
        st[tid][12] = 0.f;
    }
    __syncthreads();

    const int w = tid >> 6, lane = tid & 63;
    const int m0 = w * 1024 + lane;
    const float4* tpb = (const float4*)ptgt4 + ((size_t)b * MPTS + m0);
    const float* ps = psrc + ((size_t)b * NPTS + n0) * 3;

    for (int step = 0; step < NSTEPS; ++step) {
        float R00 = st[b][0], R01 = st[b][1], R02 = st[b][2];
        float R10 = st[b][3], R11 = st[b][4], R12 = st[b][5];
        float R20 = st[b][6], R21 = st[b][7], R22 = st[b][8];
        float t0 = st[b][9], t1 = st[b][10], t2 = st[b][11];

#define DECLP(i) float px##i, py##i, pz##i;
        FOR16(DECLP)
#undef DECLP
#define LOADP(i) { float x = ps[3*(i)], y = ps[3*(i)+1], z = ps[3*(i)+2]; \
        px##i = fmaf(R00, x, fmaf(R01, y, fmaf(R02, z, t0))); \
        py##i = fmaf(R10, x, fmaf(R11, y, fmaf(R12, z, t1))); \
        pz##i = fmaf(R20, x, fmaf(R21, y, fmaf(R22, z, t2))); }
        FOR16(LOADP)
#undef LOADP

        // s = p.t - |t|^2/2; argmax s == argmin dist (strict > keeps first max)
#define DECLB(i) float bs##i = -3.0e38f; int ix##i = m0;
        FOR16(DECLB)
#undef DECLB

        float4 tc0 = tpb[0];
        float4 tc1 = tpb[64];
        int mreg = m0;
#pragma unroll
        for (int k = 0; k < 16; ++k) {
            float4 tnx = tpb[((k + 2) & 15) * 64];  // wraps harmlessly
            float tx = tc0.x, ty = tc0.y, tz = tc0.z, htn = tc0.w;
#define PAIR(i) { float s = fmaf(px##i, tx, fmaf(py##i, ty, fmaf(pz##i, tz, -htn))); \
            if (s > bs##i) { bs##i = s; ix##i = mreg; } }
            FOR16(PAIR)
#undef PAIR
            mreg += 64;
            tc0 = tc1;
            tc1 = tnx;
        }

        // ---- wave argmax: order-preserving packed key (score hi-20 |
        // 4095-m), payload-halving fold butterfly: rounds xor 1,2,4,8 halve
        // the per-lane point set; rounds 16,32 finish the wave. 32 shuffles
        // (was 96), bitwise-identical result (HW-verified R11). ----
        unsigned k_[16];
#define MKKEY(i) { unsigned ub = __float_as_uint(bs##i); \
        unsigned u = ((int)ub >= 0) ? (ub | 0x80000000u) : ~ub; \
        k_[i] = (u & 0xFFFFF000u) | (4095u - (unsigned)ix##i); }
        FOR16(MKKEY)
#undef MKKEY
#pragma unroll
        for (int r = 0; r < 4; ++r) {
            const int mm = 1 << r;
            const int W = 16 >> r;
            unsigned o_[16];
#pragma unroll
            for (int j = 0; j < W; ++j)
                o_[j] = (unsigned)__shfl_xor((int)k_[j], mm);
            const bool hi = (lane & mm) != 0;
#pragma unroll
            for (int j = 0; j < W / 2; ++j) {
                unsigned a = hi ? k_[j + W / 2] : k_[j];
                unsigned c = hi ? o_[j + W / 2] : o_[j];
                k_[j] = a > c ? a : c;
            }
        }
        {
            unsigned o = (unsigned)__shfl_xor((int)k_[0], 16);
            k_[0] = k_[0] > o ? k_[0] : o;
            o = (unsigned)__shfl_xor((int)k_[0], 32);
            k_[0] = k_[0] > o ? k_[0] : o;
        }
        if (lane < 16) {
            // lane l holds point bitrev4(l) of its group; write to that slot
            int p = ((lane & 1) << 3) | ((lane & 2) << 1) |
                    ((lane & 4) >> 1) | ((lane & 8) >> 3);
            keys[w][p] = k_[0];
        }
        __syncthreads();

        // ---- block-combine + per-point row + partial sum + acc store:
        // all in wave 0, lanes 0-15. No barrier needed between red[] write
        // and read: same wave, LDS ops ordered via lgkmcnt. ----
        if (tid < 16) {
            unsigned key = keys[0][tid];
            unsigned k1 = keys[1][tid], k2 = keys[2][tid], k3 = keys[3][tid];
            key = key > k1 ? key : k1;
            key = key > k2 ? key : k2;
            key = key > k3 ? key : k3;
            int m = 4095 - (int)(key & 0xFFFu);
            float4 qq = ((const float4*)ptgt4)[(size_t)b * MPTS + m];
            const float* pp = psrc + ((size_t)b * NPTS + n0 + tid) * 3;
            float x = pp[0], y = pp[1], z = pp[2];
            float px = fmaf(R00, x, fmaf(R01, y, fmaf(R02, z, t0)));
            float py = fmaf(R10, x, fmaf(R11, y, fmaf(R12, z, t1)));
            float pz = fmaf(R20, x, fmaf(R21, y, fmaf(R22, z, t2)));
            float dx = px - qq.x, dy = py - qq.y, dz = pz - qq.z;
            float dist = sqrtf(dx * dx + dy * dy + dz * dz);
            red[tid][0] = px; red[tid][1] = py; red[tid][2] = pz;
            red[tid][3] = qq.x; red[tid][4] = qq.y; red[tid][5] = qq.z;
            red[tid][6] = px * qq.x;  red[tid][7] = px * qq.y;  red[tid][8] = px * qq.z;
            red[tid][9] = py * qq.x;  red[tid][10] = py * qq.y; red[tid][11] = py * qq.z;
            red[tid][12] = pz * qq.x; red[tid][13] = pz * qq.y; red[tid][14] = pz * qq.z;
            red[tid][15] = dist;
            float s = 0.f;
#pragma unroll
            for (int r = 0; r < 16; ++r) s += red[r][tid];
            __hip_atomic_store(&acc[((size_t)step * NBLK + bid) * 16 + tid], s,
                               __ATOMIC_RELAXED, __HIP_MEMORY_SCOPE_AGENT);
        }

        unsigned* stepc = ctrs + step * CTR_STRIDE;
        __syncthreads();   // drains the acc stores before arrival RMW

        if (step == NSTEPS - 1) {
            // ---- final step: workers arrive and exit; block 0 polls the
            // master counter, gathers, solves, writes out (below loop). ----
            if (tid == 0) {
                unsigned* sub = stepc + (bid & (NSUB - 1)) * 16;
                unsigned old = __hip_atomic_fetch_add(sub, 1u, __ATOMIC_RELAXED,
                                                      __HIP_MEMORY_SCOPE_AGENT);
                if (old == (unsigned)(NBLK / NSUB) - 1u)
                    __hip_atomic_fetch_add(stepc + 512, 1u, __ATOMIC_RELAXED,
                                           __HIP_MEMORY_SCOPE_AGENT);
            }
            if (bid != 0) return;   // workers done; st/out untouched by them
            if (tid == 0) {
                while (__hip_atomic_load(stepc + 512, __ATOMIC_RELAXED,
                                         __HIP_MEMORY_SCOPE_AGENT) < (unsigned)NSUB) {
                    __builtin_amdgcn_s_sleep(1);
                }
            }
            __syncthreads();
        } else {
            // ---- R9 barrier: sub RMW -> master RMW; global-last arriver
            // broadcasts 32 striped flags; everyone else polls its flag. ----
            if (tid == 0) {
                unsigned* sub = stepc + (bid & (NSUB - 1)) * 16;
                bool bcast = false;
                unsigned old = __hip_atomic_fetch_add(sub, 1u, __ATOMIC_RELAXED,
                                                      __HIP_MEMORY_SCOPE_AGENT);
                if (old == (unsigned)(NBLK / NSUB) - 1u) {
                    unsigned mold = __hip_atomic_fetch_add(stepc + 512, 1u,
                                        __ATOMIC_RELAXED, __HIP_MEMORY_SCOPE_AGENT);
                    if (mold == (unsigned)NSUB - 1u) {
#pragma unroll
                        for (int f = 0; f < NSUB; ++f)
                            __hip_atomic_store(stepc + 1024 + f * 16, 1u,
                                               __ATOMIC_RELAXED,
                                               __HIP_MEMORY_SCOPE_AGENT);
                        bcast = true;
                    }
                }
                if (!bcast) {
                    unsigned* myflag = stepc + 1024 + (bid & (NSUB - 1)) * 16;
                    while (__hip_atomic_load(myflag, __ATOMIC_RELAXED,
                                             __HIP_MEMORY_SCOPE_AGENT) == 0u) {
                        __builtin_amdgcn_s_sleep(1);
                    }
                }
            }
            __syncthreads();
        }

        // ---- gather 512x16 partials with plain loads (fresh per-step
        // region; atomic stores bypassed L2 -> L3 serves). Fixed summation
        // order -> bit-identical st grid-wide. Final step: block 0 only. ----
        {
            const float* accs = acc + (size_t)step * NBLK * 16;
            int c = tid & 15, g = tid >> 4;       // 16 groups x 32 slots
            float ssum = 0.f;
#pragma unroll
            for (int i = 0; i < 32; ++i)
                ssum += accs[(size_t)(g * 32 + i) * 16 + c];
            gred[g][c] = ssum;
        }
        __syncthreads();
        if (tid < 32) {
            int bb = tid >> 4, c = tid & 15;
            float s = 0.f;
#pragma unroll
            for (int g = 0; g < 8; ++g) s += gred[bb * 8 + g][c];
            asum[bb][c] = s;
        }
        __syncthreads();
        if (tid == 0) {
            float err0 = asum[0][15] * (1.f / NPTS);
            float err1 = asum[1][15] * (1.f / NPTS);
            bool conv = (fabsf(err0 - st[0][12]) < ICP_TOL) &&
                        (fabsf(err1 - st[1][12]) < ICP_TOL);
            contflag = conv ? 2 : 1;
        }
        __syncthreads();
        if (contflag == 1 && tid < 2) {
            float a[16];
            for (int i = 0; i < 16; ++i) a[i] = asum[tid][i];
            const float inv_n = 1.f / NPTS;
            float pmx = a[0]*inv_n, pmy = a[1]*inv_n, pmz = a[2]*inv_n;
            float qmx = a[3]*inv_n, qmy = a[4]*inv_n, qmz = a[5]*inv_n;
            float H[3][3];
            for (int i = 0; i < 3; ++i)
                for (int j = 0; j < 3; ++j)
                    H[i][j] = a[6 + 3*i + j] - a[i]*a[3 + j]*inv_n;
            float Sxx=H[0][0], Sxy=H[0][1], Sxz=H[0][2];
            float Syx=H[1][0], Syy=H[1][1], Syz=H[1][2];
            float Szx=H[2][0], Szy=H[2][1], Szz=H[2][2];
            float Nm[4][4];
            Nm[0][0] = Sxx+Syy+Szz; Nm[0][1] = Syz-Szy;
            Nm[0][2] = Szx-Sxz;     Nm[0][3] = Sxy-Syx;
            Nm[1][1] = Sxx-Syy-Szz; Nm[1][2] = Sxy+Syx; Nm[1][3] = Szx+Sxz;
            Nm[2][2] = -Sxx+Syy-Szz; Nm[2][3] = Syz+Szy;
            Nm[3][3] = -Sxx-Syy+Szz;
            Nm[1][0]=Nm[0][1]; Nm[2][0]=Nm[0][2]; Nm[3][0]=Nm[0][3];
            Nm[2][1]=Nm[1][2]; Nm[3][1]=Nm[1][3]; Nm[3][2]=Nm[2][3];
            float qv[4];
            horn_quat(Nm, qv);
            float qw = qv[0], qx = qv[1], qy = qv[2], qz = qv[3];
            float R00n = 1.f - 2.f*(qy*qy + qz*qz);
            float R01n = 2.f*(qx*qy - qw*qz);
            float R02n = 2.f*(qx*qz + qw*qy);
            float R10n = 2.f*(qx*qy + qw*qz);
            float R11n = 1.f - 2.f*(qx*qx + qz*qz);
            float R12n = 2.f*(qy*qz - qw*qx);
            float R20n = 2.f*(qx*qz - qw*qy);
            float R21n = 2.f*(qy*qz + qw*qx);
            float R22n = 1.f - 2.f*(qx*qx + qy*qy);
            float tx = qmx - (R00n*pmx + R01n*pmy + R02n*pmz);
            float ty = qmy - (R10n*pmx + R11n*pmy + R12n*pmz);
            float tz = qmz - (R20n*pmx + R21n*pmy + R22n*pmz);
            float C00=st[tid][0], C01=st[tid][1], C02=st[tid][2];
            float C10=st[tid][3], C11=st[tid][4], C12=st[tid][5];
            float C20=st[tid][6], C21=st[tid][7], C22=st[tid][8];
            float T0=st[tid][9], T1=st[tid][10], T2=st[tid][11];
            float ns[12];
            ns[0] = R00n*C00 + R01n*C10 + R02n*C20;
            ns[1] = R00n*C01 + R01n*C11 + R02n*C21;
            ns[2] = R00n*C02 + R01n*C12 + R02n*C22;
            ns[3] = R10n*C00 + R11n*C10 + R12n*C20;
            ns[4] = R10n*C01 + R11n*C11 + R12n*C21;
            ns[5] = R10n*C02 + R11n*C12 + R12n*C22;
            ns[6] = R20n*C00 + R21n*C10 + R22n*C20;
            ns[7] = R20n*C01 + R21n*C11 + R22n*C21;
            ns[8] = R20n*C02 + R21n*C12 + R22n*C22;
            ns[9]  = R00n*T0 + R01n*T1 + R02n*T2 + tx;
            ns[10] = R10n*T0 + R11n*T1 + R12n*T2 + ty;
            ns[11] = R20n*T0 + R21n*T1 + R22n*T2 + tz;
            for (int i = 0; i < 12; ++i) st[tid][i] = ns[i];
            st[tid][12] = asum[tid][15] * (1.f / NPTS);   // errnew
        }
        __syncthreads();   // st visible to all threads before next step
        if (contflag == 2) break;   // uniform across surviving blocks
    }

    if (bid == 0 && tid < 2) {
        float r00 = st[tid][0], r01 = st[tid][1], r02 = st[tid][2];
        float r10 = st[tid][3], r11 = st[tid][4], r12 = st[tid][5];
        float r20 = st[tid][6], r21 = st[tid][7], r22 = st[tid][8];
        float qw = 0.5f * sqrtf(fmaxf(1.f + r00 + r11 + r22, 1e-12f));
        float qx = 0.5f * sqrtf(fmaxf(1.f + r00 - r11 - r22, 1e-12f));
        float qy = 0.5f * sqrtf(fmaxf(1.f - r00 + r11 - r22, 1e-12f));
        float qz = 0.5f * sqrtf(fmaxf(1.f - r00 - r11 + r22, 1e-12f));
        qx = (r21 - r12 >= 0.f) ? qx : -qx;
        qy = (r02 - r20 >= 0.f) ? qy : -qy;
        qz = (r10 - r01 >= 0.f) ? qz : -qz;
        out[tid * 7 + 0] = st[tid][9];
        out[tid * 7 + 1] = st[tid][10];
        out[tid * 7 + 2] = st[tid][11];
        out[tid * 7 + 3] = qx;
        out[tid * 7 + 4] = qy;
        out[tid * 7 + 5] = qz;
        out[tid * 7 + 6] = qw;
    }
}

extern "C" void kernel_launch(void* const* d_in, const int* in_sizes, int n_in,
                              void* d_out, int out_size, void* d_ws, size_t ws_size,
                              hipStream_t stream) {
    const float* psrc = (const float*)d_in[0];
    const float* ptgt = (const float*)d_in[1];
    float* out = (float*)d_out;
    float* ws = (float*)d_ws;

    init_kernel<<<32, 256, 0, stream>>>(ptgt, ws);
    icp_main<<<NBLK, 256, 0, stream>>>(psrc, ws, out);
}

// Round 10
// 158.961 us; speedup vs baseline: 1.1314x; 1.0128x over previous
//
#include <hip/hip_runtime.h>
#include <math.h>

#define NPTS 4096
#define MPTS 4096
#define NSTEPS 8
#define ICP_TOL 1e-6f
#define NBLK 512    // 2 blocks/CU @ launch_bounds(256,2): proven resident, no spill (R5-R17)
#define NSUB 32     // arrival sub-counters, 16 blocks each

// ws layout (floats):
//   ptgt4 : [0, 32768)         interleaved {x,y,z,0.5*|t|^2}, 2*4096 targets
//   acc   : [32768, 98304)     [step][block(512)][16] per-block partials (atomic stores)
//   ctrs  : words at 98304, 1536/step: subs at c*16 (c<32), master at 512,
//           flags at 1024+f*16 (f<32); value 0=wait, 1=released
#define ACC_OFF 32768
#define CTR_OFF 98304
#define CTR_STRIDE 1536

__global__ void init_kernel(const float* __restrict__ ptgt, float* __restrict__ ws) {
    float* ptgt4 = ws;
    unsigned* ctrs = (unsigned*)(ws + CTR_OFF);
    int gid = blockIdx.x * 256 + threadIdx.x;   // 8192 threads
    if (gid < 2 * MPTS) {
        float x = ptgt[3 * gid + 0];
        float y = ptgt[3 * gid + 1];
        float z = ptgt[3 * gid + 2];
        float4 v;
        v.x = x; v.y = y; v.z = z;
        v.w = 0.5f * (x * x + y * y + z * z);
        ((float4*)ptgt4)[gid] = v;
    }
    for (int i = gid; i < NSTEPS * CTR_STRIDE; i += 8192) ctrs[i] = 0u;
}

__device__ __forceinline__ float frcp(float x) {
#if __has_builtin(__builtin_amdgcn_rcpf)
    return __builtin_amdgcn_rcpf(x);
#else
    return 1.f / x;
#endif
}
__device__ __forceinline__ float frsq(float x) {
#if __has_builtin(__builtin_amdgcn_rsqf)
    return __builtin_amdgcn_rsqf(x);
#else
    return 1.f / sqrtf(x);
#endif
}

#define DET3(a,b,c,d,e,f,g,h,i) \
    ((a)*((e)*(i)-(f)*(h)) - (b)*((d)*(i)-(f)*(g)) + (c)*((d)*(h)-(e)*(g)))

// Max-eigenpair of symmetric 4x4 via Newton on the characteristic quartic
// (monotone from Gershgorin upper bound) + cofactor-row eigenvector.
// 8 Newton iterations: quadratic convergence, rel err < 1e-12 by 8; canary-
// verified bitwise-stable vs 12 its (R13/R14 absmax unchanged).
__device__ __forceinline__ void horn_quat(const float N[4][4], float q[4]) {
    float s = 1e-30f;
#pragma unroll
    for (int i = 0; i < 4; ++i)
#pragma unroll
        for (int j = 0; j < 4; ++j) s = fmaxf(s, fabsf(N[i][j]));
    float inv = frcp(s);
    float A[4][4], B[4][4];
#pragma unroll
    for (int i = 0; i < 4; ++i)
#pragma unroll
        for (int j = 0; j < 4; ++j) A[i][j] = N[i][j] * inv;
#pragma unroll
    for (int i = 0; i < 4; ++i)
#pragma unroll
        for (int j = i; j < 4; ++j) {
            float v = A[i][0]*A[0][j] + A[i][1]*A[1][j] + A[i][2]*A[2][j] + A[i][3]*A[3][j];
            B[i][j] = v; B[j][i] = v;
        }
    float p1 = A[0][0]+A[1][1]+A[2][2]+A[3][3];
    float p2 = B[0][0]+B[1][1]+B[2][2]+B[3][3];
    float p3 = 0.f, p4 = 0.f;
#pragma unroll
    for (int i = 0; i < 4; ++i)
#pragma unroll
        for (int j = 0; j < 4; ++j) { p3 += A[i][j]*B[i][j]; p4 += B[i][j]*B[i][j]; }
    float e1 = p1;
    float e2 = 0.5f*(e1*p1 - p2);
    float e3 = (e2*p1 - e1*p2 + p3)*(1.f/3.f);
    float e4 = 0.25f*(e3*p1 - e2*p2 + e1*p3 - p4);
    float lam = -3e38f;
#pragma unroll
    for (int i = 0; i < 4; ++i) {
        float r = A[i][i];
#pragma unroll
        for (int j = 0; j < 4; ++j) if (j != i) r += fabsf(A[i][j]);
        lam = fmaxf(lam, r);
    }
#pragma unroll
    for (int it = 0; it < 8; ++it) {
        float pv = (((lam - e1)*lam + e2)*lam - e3)*lam + e4;
        float dv = ((4.f*lam - 3.f*e1)*lam + 2.f*e2)*lam - e3;
        lam -= pv * frcp(dv);
    }
    float M[4][4];
#pragma unroll
    for (int i = 0; i < 4; ++i)
#pragma unroll
        for (int j = 0; j < 4; ++j) M[i][j] = A[i][j] - ((i == j) ? lam : 0.f);
    float C0 = DET3(M[1][1],M[1][2],M[1][3], M[2][1],M[2][2],M[2][3], M[3][1],M[3][2],M[3][3]);
    float C1 = DET3(M[0][0],M[0][2],M[0][3], M[2][0],M[2][2],M[2][3], M[3][0],M[3][2],M[3][3]);
    float C2 = DET3(M[0][0],M[0][1],M[0][3], M[1][0],M[1][1],M[1][3], M[3][0],M[3][1],M[3][3]);
    float C3 = DET3(M[0][0],M[0][1],M[0][2], M[1][0],M[1][1],M[1][2], M[2][0],M[2][1],M[2][2]);
    int is = 0; float cb = fabsf(C0);
    if (fabsf(C1) > cb) { cb = fabsf(C1); is = 1; }
    if (fabsf(C2) > cb) { cb = fabsf(C2); is = 2; }
    if (fabsf(C3) > cb) { cb = fabsf(C3); is = 3; }
    float v0, v1, v2, v3;
#define ROWCOF(a,b,c) { \
    v0 =  DET3(M[a][1],M[a][2],M[a][3], M[b][1],M[b][2],M[b][3], M[c][1],M[c][2],M[c][3]); \
    v1 = -DET3(M[a][0],M[a][2],M[a][3], M[b][0],M[b][2],M[b][3], M[c][0],M[c][2],M[c][3]); \
    v2 =  DET3(M[a][0],M[a][1],M[a][3], M[b][0],M[b][1],M[b][3], M[c][0],M[c][1],M[c][3]); \
    v3 = -DET3(M[a][0],M[a][1],M[a][2], M[b][0],M[b][1],M[b][2], M[c][0],M[c][1],M[c][2]); }
    if (is == 0)      ROWCOF(1,2,3)
    else if (is == 1) ROWCOF(0,2,3)
    else if (is == 2) ROWCOF(0,1,3)
    else              ROWCOF(0,1,2)
#undef ROWCOF
    float nr = frsq(v0*v0 + v1*v1 + v2*v2 + v3*v3);
    q[0] = v0*nr; q[1] = v1*nr; q[2] = v2*nr; q[3] = v3*nr;
}

#define FOR16(OP) OP(0) OP(1) OP(2) OP(3) OP(4) OP(5) OP(6) OP(7) \
                  OP(8) OP(9) OP(10) OP(11) OP(12) OP(13) OP(14) OP(15)

// R18 = R16 content resubmitted after R17's control run proved the R15/R16
// failures were environment-side (byte-exact R12 passed at 114.9us, counters
// identical to Round 4). Structure: exact R12 topology (114us proven twice)
// + Newton 12->8 (canary-proven R13/R14) + dual-accumulator gather chain
// (pure reassociation) + bounded polls (zero-cost hardening). R13/R14's
// per-batch-gather tail recorded as anti-pattern (+20us stall at identical
// VALU-busy).
__global__ __launch_bounds__(256, 2) void icp_main(
    const float* __restrict__ psrc, float* __restrict__ ws,
    float* __restrict__ out) {

    float* ptgt4 = ws;
    float* acc = ws + ACC_OFF;
    unsigned* ctrs = (unsigned*)(ws + CTR_OFF);

    __shared__ float st[2][13];     // per batch: Rcum(9), tcum(3), err(1)
    __shared__ unsigned keys[4][16];
    __shared__ float red[16][16];
    __shared__ float gred[16][16];  // gather partials [group][comp]
    __shared__ float asum[2][16];
    __shared__ int contflag;        // 1=continue, 2=done

    const int tid = threadIdx.x;
    const int bid = blockIdx.x;
    const int b = bid >> 8;             // batch (256 blocks each)
    const int n0 = (bid & 255) * 16;    // this block's 16 source points

    if (tid < 2) {
        st[tid][0] = 1.f; st[tid][1] = 0.f; st[tid][2] = 0.f;
        st[tid][3] = 0.f; st[tid][4] = 1.f; st[tid][5] = 0.f;
        st[tid][6] = 0.f; st[tid][7] = 0.f; st[tid][8] = 1.f;
        st[tid][9] = 0.f; st[tid][10] = 0.f; st[tid][11] = 0.f;
        st[tid][12] = 0.f;
    }
    __syncthreads();

    const int w = tid >> 6, lane = tid & 63;
    const int m0 = w * 1024 + lane;
    const float4* tpb = (const float4*)ptgt4 + ((size_t)b * MPTS + m0);
    const float* ps = psrc + ((size_t)b * NPTS + n0) * 3;

    for (int step = 0; step < NSTEPS; ++step) {
        float R00 = st[b][0], R01 = st[b][1], R02 = st[b][2];
        float R10 = st[b][3], R11 = st[b][4], R12 = st[b][5];
        float R20 = st[b][6], R21 = st[b][7], R22 = st[b][8];
        float t0 = st[b][9], t1 = st[b][10], t2 = st[b][11];

#define DECLP(i) float px##i, py##i, pz##i;
        FOR16(DECLP)
#undef DECLP
#define LOADP(i) { float x = ps[3*(i)], y = ps[3*(i)+1], z = ps[3*(i)+2]; \
        px##i = fmaf(R00, x, fmaf(R01, y, fmaf(R02, z, t0))); \
        py##i = fmaf(R10, x, fmaf(R11, y, fmaf(R12, z, t1))); \
        pz##i = fmaf(R20, x, fmaf(R21, y, fmaf(R22, z, t2))); }
        FOR16(LOADP)
#undef LOADP

        // s = p.t - |t|^2/2; argmax s == argmin dist (strict > keeps first max)
#define DECLB(i) float bs##i = -3.0e38f; int ix##i = m0;
        FOR16(DECLB)
#undef DECLB

        float4 tc0 = tpb[0];
        float4 tc1 = tpb[64];
        int mreg = m0;
#pragma unroll
        for (int k = 0; k < 16; ++k) {
            float4 tnx = tpb[((k + 2) & 15) * 64];  // wraps harmlessly
            float tx = tc0.x, ty = tc0.y, tz = tc0.z, htn = tc0.w;
#define PAIR(i) { float s = fmaf(px##i, tx, fmaf(py##i, ty, fmaf(pz##i, tz, -htn))); \
            if (s > bs##i) { bs##i = s; ix##i = mreg; } }
            FOR16(PAIR)
#undef PAIR
            mreg += 64;
            tc0 = tc1;
            tc1 = tnx;
        }

        // ---- wave argmax: order-preserving packed key (score hi-20 |
        // 4095-m), payload-halving fold butterfly (32 shuffles, HW-verified
        // bitwise == 96-shuffle tree, R11/R12/R17). ----
        unsigned k_[16];
#define MKKEY(i) { unsigned ub = __float_as_uint(bs##i); \
        unsigned u = ((int)ub >= 0) ? (ub | 0x80000000u) : ~ub; \
        k_[i] = (u & 0xFFFFF000u) | (4095u - (unsigned)ix##i); }
        FOR16(MKKEY)
#undef MKKEY
#pragma unroll
        for (int r = 0; r < 4; ++r) {
            const int mm = 1 << r;
            const int W = 16 >> r;
            unsigned o_[16];
#pragma unroll
            for (int j = 0; j < W; ++j)
                o_[j] = (unsigned)__shfl_xor((int)k_[j], mm);
            const bool hi = (lane & mm) != 0;
#pragma unroll
            for (int j = 0; j < W / 2; ++j) {
                unsigned a = hi ? k_[j + W / 2] : k_[j];
                unsigned c = hi ? o_[j + W / 2] : o_[j];
                k_[j] = a > c ? a : c;
            }
        }
        {
            unsigned o = (unsigned)__shfl_xor((int)k_[0], 16);
            k_[0] = k_[0] > o ? k_[0] : o;
            o = (unsigned)__shfl_xor((int)k_[0], 32);
            k_[0] = k_[0] > o ? k_[0] : o;
        }
        if (lane < 16) {
            int p = ((lane & 1) << 3) | ((lane & 2) << 1) |
                    ((lane & 4) >> 1) | ((lane & 8) >> 3);
            keys[w][p] = k_[0];
        }
        __syncthreads();

        // ---- block-combine + per-point row + serial partial sum + acc
        // store: all in wave 0, lanes 0-15 (same-wave LDS ordered via
        // lgkmcnt, no extra barriers). ----
        if (tid < 16) {
            unsigned key = keys[0][tid];
            unsigned k1 = keys[1][tid], k2 = keys[2][tid], k3 = keys[3][tid];
            key = key > k1 ? key : k1;
            key = key > k2 ? key : k2;
            key = key > k3 ? key : k3;
            int m = 4095 - (int)(key & 0xFFFu);
            float4 qq = ((const float4*)ptgt4)[(size_t)b * MPTS + m];
            const float* pp = psrc + ((size_t)b * NPTS + n0 + tid) * 3;
            float x = pp[0], y = pp[1], z = pp[2];
            float px = fmaf(R00, x, fmaf(R01, y, fmaf(R02, z, t0)));
            float py = fmaf(R10, x, fmaf(R11, y, fmaf(R12, z, t1)));
            float pz = fmaf(R20, x, fmaf(R21, y, fmaf(R22, z, t2)));
            float dx = px - qq.x, dy = py - qq.y, dz = pz - qq.z;
            float dist = sqrtf(dx * dx + dy * dy + dz * dz);
            red[tid][0] = px; red[tid][1] = py; red[tid][2] = pz;
            red[tid][3] = qq.x; red[tid][4] = qq.y; red[tid][5] = qq.z;
            red[tid][6] = px * qq.x;  red[tid][7] = px * qq.y;  red[tid][8] = px * qq.z;
            red[tid][9] = py * qq.x;  red[tid][10] = py * qq.y; red[tid][11] = py * qq.z;
            red[tid][12] = pz * qq.x; red[tid][13] = pz * qq.y; red[tid][14] = pz * qq.z;
            red[tid][15] = dist;
            float s = 0.f;
#pragma unroll
            for (int r = 0; r < 16; ++r) s += red[r][tid];
            __hip_atomic_store(&acc[((size_t)step * NBLK + bid) * 16 + tid], s,
                               __ATOMIC_RELAXED, __HIP_MEMORY_SCOPE_AGENT);
        }

        unsigned* stepc = ctrs + step * CTR_STRIDE;
        __syncthreads();   // drains the acc stores before arrival RMW

        if (step == NSTEPS - 1) {
            // ---- final step: workers arrive and exit; block 0 polls the
            // master counter, gathers, solves both batches, writes out. ----
            if (tid == 0) {
                unsigned* sub = stepc + (bid & (NSUB - 1)) * 16;
                unsigned old = __hip_atomic_fetch_add(sub, 1u, __ATOMIC_RELAXED,
                                                      __HIP_MEMORY_SCOPE_AGENT);
                if (old == (unsigned)(NBLK / NSUB) - 1u)
                    __hip_atomic_fetch_add(stepc + 512, 1u, __ATOMIC_RELAXED,
                                           __HIP_MEMORY_SCOPE_AGENT);
            }
            if (bid != 0) return;   // workers done; st/out untouched by them
            if (tid == 0) {
                int spin = 0;
                while (__hip_atomic_load(stepc + 512, __ATOMIC_RELAXED,
                                         __HIP_MEMORY_SCOPE_AGENT) < (unsigned)NSUB) {
                    if (++spin > (1 << 20)) break;   // failsafe, unreachable
                    __builtin_amdgcn_s_sleep(1);
                }
            }
            __syncthreads();
        } else {
            // ---- R9 barrier: sub RMW -> master RMW; global-last arriver
            // broadcasts 32 striped flags; everyone else polls its flag. ----
            if (tid == 0) {
                unsigned* sub = stepc + (bid & (NSUB - 1)) * 16;
                bool bcast = false;
                unsigned old = __hip_atomic_fetch_add(sub, 1u, __ATOMIC_RELAXED,
                                                      __HIP_MEMORY_SCOPE_AGENT);
                if (old == (unsigned)(NBLK / NSUB) - 1u) {
                    unsigned mold = __hip_atomic_fetch_add(stepc + 512, 1u,
                                        __ATOMIC_RELAXED, __HIP_MEMORY_SCOPE_AGENT);
                    if (mold == (unsigned)NSUB - 1u) {
#pragma unroll
                        for (int f = 0; f < NSUB; ++f)
                            __hip_atomic_store(stepc + 1024 + f * 16, 1u,
                                               __ATOMIC_RELAXED,
                                               __HIP_MEMORY_SCOPE_AGENT);
                        bcast = true;
                    }
                }
                if (!bcast) {
                    unsigned* myflag = stepc + 1024 + (bid & (NSUB - 1)) * 16;
                    int spin = 0;
                    while (__hip_atomic_load(myflag, __ATOMIC_RELAXED,
                                             __HIP_MEMORY_SCOPE_AGENT) == 0u) {
                        if (++spin > (1 << 20)) break;   // failsafe, unreachable
                        __builtin_amdgcn_s_sleep(1);
                    }
                }
            }
            __syncthreads();
        }

        // ---- gather 512x16 partials with coalesced plain loads (fresh
        // per-step region; atomic stores bypassed L2 -> L3 serves). Dual
        // accumulators halve the dependent fadd chain (2x16 + add). ----
        {
            const float* accs = acc + (size_t)step * NBLK * 16;
            int c = tid & 15, g = tid >> 4;       // 16 groups x 32 slots
            float s0 = 0.f, s1 = 0.f;
#pragma unroll
            for (int i = 0; i < 16; ++i) {
                s0 += accs[(size_t)(g * 32 + 2 * i) * 16 + c];
                s1 += accs[(size_t)(g * 32 + 2 * i + 1) * 16 + c];
            }
            gred[g][c] = s0 + s1;
        }
        __syncthreads();
        if (tid < 32) {
            int bb = tid >> 4, c = tid & 15;
            float s = 0.f;
#pragma unroll
            for (int g = 0; g < 8; ++g) s += gred[bb * 8 + g][c];
            asum[bb][c] = s;
        }
        __syncthreads();
        if (tid == 0) {
            float err0 = asum[0][15] * (1.f / NPTS);
            float err1 = asum[1][15] * (1.f / NPTS);
            bool conv = (fabsf(err0 - st[0][12]) < ICP_TOL) &&
                        (fabsf(err1 - st[1][12]) < ICP_TOL);
            contflag = conv ? 2 : 1;
        }
        __syncthreads();
        if (contflag == 1 && tid < 2) {
            float a[16];
            for (int i = 0; i < 16; ++i) a[i] = asum[tid][i];
            const float inv_n = 1.f / NPTS;
            float pmx = a[0]*inv_n, pmy = a[1]*inv_n, pmz = a[2]*inv_n;
            float qmx = a[3]*inv_n, qmy = a[4]*inv_n, qmz = a[5]*inv_n;
            float H[3][3];
            for (int i = 0; i < 3; ++i)
                for (int j = 0; j < 3; ++j)
                    H[i][j] = a[6 + 3*i + j] - a[i]*a[3 + j]*inv_n;
            float Sxx=H[0][0], Sxy=H[0][1], Sxz=H[0][2];
            float Syx=H[1][0], Syy=H[1][1], Syz=H[1][2];
            float Szx=H[2][0], Szy=H[2][1], Szz=H[2][2];
            float Nm[4][4];
            Nm[0][0] = Sxx+Syy+Szz; Nm[0][1] = Syz-Szy;
            Nm[0][2] = Szx-Sxz;     Nm[0][3] = Sxy-Syx;
            Nm[1][1] = Sxx-Syy-Szz; Nm[1][2] = Sxy+Syx; Nm[1][3] = Szx+Sxz;
            Nm[2][2] = -Sxx+Syy-Szz; Nm[2][3] = Syz+Szy;
            Nm[3][3] = -Sxx-Syy+Szz;
            Nm[1][0]=Nm[0][1]; Nm[2][0]=Nm[0][2]; Nm[3][0]=Nm[0][3];
            Nm[2][1]=Nm[1][2]; Nm[3][1]=Nm[1][3]; Nm[3][2]=Nm[2][3];
            float qv[4];
            horn_quat(Nm, qv);
            float qw = qv[0], qx = qv[1], qy = qv[2], qz = qv[3];
            float R00n = 1.f - 2.f*(qy*qy + qz*qz);
            float R01n = 2.f*(qx*qy - qw*qz);
            float R02n = 2.f*(qx*qz + qw*qy);
            float R10n = 2.f*(qx*qy + qw*qz);
            float R11n = 1.f - 2.f*(qx*qx + qz*qz);
            float R12n = 2.f*(qy*qz - qw*qx);
            float R20n = 2.f*(qx*qz - qw*qy);
            float R21n = 2.f*(qy*qz + qw*qx);
            float R22n = 1.f - 2.f*(qx*qx + qy*qy);
            float tx = qmx - (R00n*pmx + R01n*pmy + R02n*pmz);
            float ty = qmy - (R10n*pmx + R11n*pmy + R12n*pmz);
            float tz = qmz - (R20n*pmx + R21n*pmy + R22n*pmz);
            float C00=st[tid][0], C01=st[tid][1], C02=st[tid][2];
            float C10=st[tid][3], C11=st[tid][4], C12=st[tid][5];
            float C20=st[tid][6], C21=st[tid][7], C22=st[tid][8];
            float T0=st[tid][9], T1=st[tid][10], T2=st[tid][11];
            float ns[12];
            ns[0] = R00n*C00 + R01n*C10 + R02n*C20;
            ns[1] = R00n*C01 + R01n*C11 + R02n*C21;
            ns[2] = R00n*C02 + R01n*C12 + R02n*C22;
            ns[3] = R10n*C00 + R11n*C10 + R12n*C20;
            ns[4] = R10n*C01 + R11n*C11 + R12n*C21;
            ns[5] = R10n*C02 + R11n*C12 + R12n*C22;
            ns[6] = R20n*C00 + R21n*C10 + R22n*C20;
            ns[7] = R20n*C01 + R21n*C11 + R22n*C21;
            ns[8] = R20n*C02 + R21n*C12 + R22n*C22;
            ns[9]  = R00n*T0 + R01n*T1 + R02n*T2 + tx;
            ns[10] = R10n*T0 + R11n*T1 + R12n*T2 + ty;
            ns[11] = R20n*T0 + R21n*T1 + R22n*T2 + tz;
            for (int i = 0; i < 12; ++i) st[tid][i] = ns[i];
            st[tid][12] = asum[tid][15] * (1.f / NPTS);   // errnew
        }
        __syncthreads();   // st visible to all threads before next step
        if (contflag == 2) break;   // uniform across surviving blocks
    }

    if (bid == 0 && tid < 2) {
        float r00 = st[tid][0], r01 = st[tid][1], r02 = st[tid][2];
        float r10 = st[tid][3], r11 = st[tid][4], r12 = st[tid][5];
        float r20 = st[tid][6], r21 = st[tid][7], r22 = st[tid][8];
        float qw = 0.5f * sqrtf(fmaxf(1.f + r00 + r11 + r22, 1e-12f));
        float qx = 0.5f * sqrtf(fmaxf(1.f + r00 - r11 - r22, 1e-12f));
        float qy = 0.5f * sqrtf(fmaxf(1.f - r00 + r11 - r22, 1e-12f));
        float qz = 0.5f * sqrtf(fmaxf(1.f - r00 - r11 + r22, 1e-12f));
        qx = (r21 - r12 >= 0.f) ? qx : -qx;
        qy = (r02 - r20 >= 0.f) ? qy : -qy;
        qz = (r10 - r01 >= 0.f) ? qz : -qz;
        out[tid * 7 + 0] = st[tid][9];
        out[tid * 7 + 1] = st[tid][10];
        out[tid * 7 + 2] = st[tid][11];
        out[tid * 7 + 3] = qx;
        out[tid * 7 + 4] = qy;
        out[tid * 7 + 5] = qz;
        out[tid * 7 + 6] = qw;
    }
}

extern "C" void kernel_launch(void* const* d_in, const int* in_sizes, int n_in,
                              void* d_out, int out_size, void* d_ws, size_t ws_size,
                              hipStream_t stream) {
    const float* psrc = (const float*)d_in[0];
    const float* ptgt = (const float*)d_in[1];
    float* out = (float*)d_out;
    float* ws = (float*)d_ws;

    init_kernel<<<32, 256, 0, stream>>>(ptgt, ws);
    icp_main<<<NBLK, 256, 0, stream>>>(psrc, ws, out);
}